// Round 6
// baseline (17930.679 us; speedup 1.0000x reference)
//
#include <hip/hip_runtime.h>
#include <cstdint>
#include <cstddef>

// ---------------- constants ----------------
#define FHW   32
#define CCH   128
#define NAq   9216
#define NW1   144
#define KP    2000
#define NW2   32
#define HID   1024
#define KFC1  6272

// output offsets (floats)
#define OFF_LOGITS 0
#define OFF_DELTAS 18432
#define OFF_PROPS  55296
#define OFF_ANCH   63296
#define OFF_RLOG   100160
#define OFF_RDEL   104160
#define OFF_DETS   112160
#define OFF_SC     120160

typedef unsigned long long ull;

// f32 anchor, replicating reference op order exactly
__device__ __forceinline__ void anchor_f32(int n, float* a4){
    int a = n % 9, j = (n/9) % FHW, i = n / (9*FHW);
    const float scales[3] = {32.f, 64.f, 128.f};
    const float ratios[3] = {0.5f, 1.f, 2.f};
    float s = scales[a/3], r = ratios[a%3];
    float sq = sqrtf(r);
    float ws = s / sq, hs = s * sq;
    float cx = ((float)j + 0.5f) * 16.f, cy = ((float)i + 0.5f) * 16.f;
    float W2 = ws * 0.5f, H2 = hs * 0.5f;
    a4[0] = cx - W2; a4[1] = cy - H2; a4[2] = cx + W2; a4[3] = cy + H2;
}

__global__ void anchors_k(float* __restrict__ outA){
    int n = blockIdx.x*blockDim.x + threadIdx.x;
    if (n >= NAq) return;
    float a4[4]; anchor_f32(n, a4);
    ((float4*)outA)[n] = make_float4(a4[0], a4[1], a4[2], a4[3]);
}

// ---------------- weight transposes (f32 -> f64) ----------------
__global__ void transb_k(const float* __restrict__ w, double* __restrict__ wT){
    int idx = blockIdx.x*blockDim.x + threadIdx.x;
    if (idx >= CCH*768) return;
    int oc = idx / 768, t = idx % 768;
    wT[t*CCH + oc] = (double)w[idx];
}
__global__ void transw_k(const float* __restrict__ w, double* __restrict__ wT){
    int idx = blockIdx.x*blockDim.x + threadIdx.x;
    if (idx >= CCH*CCH*9) return;
    int oc = idx / (CCH*9);
    int rem = idx % (CCH*9);
    int ic = rem / 9, p = rem % 9;
    wT[(p*CCH + ic)*CCH + oc] = (double)w[idx];
}

// ---------------- backbone conv (f64 accum), writes f64 + f32 copies ----------------
__global__ __launch_bounds__(128) void backbone_k(const float* __restrict__ x,
    const double* __restrict__ wT, const float* __restrict__ b,
    double* __restrict__ featD, float* __restrict__ featF){
    __shared__ double patch[768];
    int j = blockIdx.x, i = blockIdx.y, tid = threadIdx.x;
    for (int t = tid; t < 768; t += 128){
        int ch = t >> 8, rem = t & 255, r = rem >> 4, cl = rem & 15;
        patch[t] = (double)x[ch*512*512 + (i*16 + r)*512 + j*16 + cl];
    }
    __syncthreads();
    double acc = (double)b[tid];
    #pragma unroll 4
    for (int t = 0; t < 768; t++) acc += patch[t] * wT[t*CCH + tid];
    double v = fmax(acc, 0.0);
    featD[(i*FHW + j)*CCH + tid] = v;
    featF[(i*FHW + j)*CCH + tid] = (float)v;
}

// ---------------- rpn 3x3 conv (f64) ----------------
__global__ __launch_bounds__(128) void rpnconv_k(const double* __restrict__ feat,
    const double* __restrict__ wT, const float* __restrict__ b,
    double* __restrict__ h){
    __shared__ double patch[9*CCH];
    int j = blockIdx.x, i = blockIdx.y, tid = threadIdx.x;
    for (int t = tid; t < 9*CCH; t += 128){
        int p = t >> 7, ic = t & 127;
        int y = i + p/3 - 1, xx = j + p%3 - 1;
        patch[t] = (y >= 0 && y < FHW && xx >= 0 && xx < FHW) ? feat[(y*FHW + xx)*CCH + ic] : 0.0;
    }
    __syncthreads();
    double acc = (double)b[tid];
    #pragma unroll 4
    for (int t = 0; t < 9*CCH; t++) acc += patch[t] * wT[t*CCH + tid];
    h[(i*FHW + j)*CCH + tid] = fmax(acc, 0.0);
}

// ---------------- rpn heads: f64 dot, f32 softmax/decode/clip ----------------
__global__ __launch_bounds__(64) void rpnhead_k(const double* __restrict__ h,
    const float* __restrict__ wc, const float* __restrict__ bc,
    const float* __restrict__ wr, const float* __restrict__ br,
    float* __restrict__ outLog, float* __restrict__ outDel,
    float* __restrict__ boxes, float* __restrict__ scores){
    __shared__ double hv[CCH];
    __shared__ double ov[54];
    int pos = blockIdx.x, tid = threadIdx.x;
    hv[tid]      = h[pos*CCH + tid];
    hv[tid + 64] = h[pos*CCH + tid + 64];
    __syncthreads();
    if (tid < 54){
        const float* wrow; double bias;
        if (tid < 18){ wrow = wc + tid*CCH; bias = (double)bc[tid]; }
        else         { wrow = wr + (tid-18)*CCH; bias = (double)br[tid-18]; }
        double acc = bias;
        #pragma unroll 4
        for (int k = 0; k < CCH; k++) acc += hv[k] * (double)wrow[k];
        ov[tid] = acc;
    }
    __syncthreads();
    if (tid < 18) outLog[pos*18 + tid] = (float)ov[tid];
    if (tid < 36) outDel[pos*36 + tid] = (float)ov[18 + tid];
    if (tid < 9){
        int n = pos*9 + tid;
        float l0 = (float)ov[2*tid], l1 = (float)ov[2*tid+1];
        float m = fmaxf(l0, l1);
        float e0 = expf(l0 - m), e1 = expf(l1 - m);
        float s = e1 / (e0 + e1);
        float dx = (float)ov[18+4*tid+0], dy = (float)ov[18+4*tid+1];
        float dw = (float)ov[18+4*tid+2], dh = (float)ov[18+4*tid+3];
        float an[4]; anchor_f32(n, an);
        float aw = an[2] - an[0] + 1.f, ah = an[3] - an[1] + 1.f;
        float acx = an[0] + 0.5f*aw, acy = an[1] + 0.5f*ah;
        float pcx = dx*aw + acx, pcy = dy*ah + acy;
        float pw = expf(dw)*aw, ph = expf(dh)*ah;
        float x1 = pcx - 0.5f*pw, y1 = pcy - 0.5f*ph;
        float x2 = pcx + 0.5f*pw, y2 = pcy + 0.5f*ph;
        x1 = fminf(fmaxf(x1, 0.f), 511.f);  y1 = fminf(fmaxf(y1, 0.f), 511.f);
        x2 = fminf(fmaxf(x2, 0.f), 511.f);  y2 = fminf(fmaxf(y2, 0.f), 511.f);
        ((float4*)boxes)[n] = make_float4(x1, y1, x2, y2);
        scores[n] = s;
    }
}

// ---------------- stable rank sort (desc score, asc index), f32 ----------------
__global__ __launch_bounds__(256) void rank_sortf(const float* __restrict__ sc,
                                                  int* __restrict__ order, int N){
    __shared__ float ss[2048];
    int i = blockIdx.x*blockDim.x + threadIdx.x;
    float mys = (i < N) ? sc[i] : -1e30f;
    int r = 0;
    for (int base = 0; base < N; base += 2048){
        int cnt = min(2048, N - base);
        __syncthreads();
        for (int t = threadIdx.x; t < cnt; t += blockDim.x) ss[t] = sc[base + t];
        __syncthreads();
        for (int j = 0; j < cnt; j++){
            float s = ss[j];
            int jg = base + j;
            r += (s > mys) || (s == mys && jg < i);
        }
    }
    if (i < N) order[r] = i;
}

__global__ void gather_sorted(const float4* __restrict__ boxes, const int* __restrict__ order,
                              float4* __restrict__ sb, int N){
    int r = blockIdx.x*blockDim.x + threadIdx.x;
    if (r < N) sb[r] = boxes[order[r]];
}

// ---------------- IoU suppression bitmask, f32 ----------------
__global__ void nms_maskf(const float4* __restrict__ sb, ull* __restrict__ mask,
                          int N, int Nw, float thr){
    int i = blockIdx.x;
    int w = threadIdx.x;
    if (w >= Nw) return;
    float4 bi = sb[i];
    float areai = (bi.z - bi.x + 1.f) * (bi.w - bi.y + 1.f);
    ull bits = 0;
    int jbase = w*64;
    if (jbase + 63 > i){
        for (int k = 0; k < 64; k++){
            int j = jbase + k;
            if (j <= i || j >= N) continue;
            float4 bj = sb[j];
            float xx1 = fmaxf(bi.x, bj.x), yy1 = fmaxf(bi.y, bj.y);
            float xx2 = fminf(bi.z, bj.z), yy2 = fminf(bi.w, bj.w);
            float iw = fmaxf(xx2 - xx1 + 1.f, 0.f), ih = fmaxf(yy2 - yy1 + 1.f, 0.f);
            float inter = iw * ih;
            float areaj = (bj.z - bj.x + 1.f) * (bj.w - bj.y + 1.f);
            float iou = inter / (areai + areaj - inter);
            if (iou > thr) bits |= (1ull << k);
        }
    }
    mask[(size_t)i*Nw + w] = bits;
}

// ---------------- single-thread serial greedy scan (trivially correct) ----------------
__global__ void nms_scan1(const ull* __restrict__ mask, const int* __restrict__ order,
                          int* __restrict__ keep, int* __restrict__ cntOut,
                          int N, int Nw, int K, int earlyStop){
    __shared__ ull removed[NW1];
    if (threadIdx.x != 0) return;
    for (int w = 0; w < Nw; w++) removed[w] = 0ull;
    for (int t = 0; t < K; t++) keep[t] = 0;
    int cnt = 0;
    for (int i = 0; i < N; i++){
        int iw = i >> 6, ib = i & 63;
        if ((removed[iw] >> ib) & 1ull) continue;
        if (cnt < K) keep[cnt] = order[i];
        cnt++;
        if (earlyStop && cnt >= K) break;
        const ull* mrow = mask + (size_t)i*Nw;
        for (int w = iw; w < Nw; w++) removed[w] |= mrow[w];
    }
    *cntOut = cnt;
}

// ---------------- gather proposals ----------------
__global__ void props_k(const float4* __restrict__ boxes, const int* __restrict__ keep1,
                        float* __restrict__ outP, float4* __restrict__ propsWs){
    int j = blockIdx.x*blockDim.x + threadIdx.x;
    if (j >= KP) return;
    float4 b = boxes[keep1[j]];
    ((float4*)outP)[j] = b;
    propsWs[j] = b;
}

// ---------------- crop_resize(14) + 2x2 maxpool, f32 ----------------
__global__ __launch_bounds__(128) void croppool_k(const float* __restrict__ feat,
    const float* __restrict__ props, float* __restrict__ pooled){
    __shared__ int   sy0[14], sy1[14], sx0[14], sx1[14];
    __shared__ float swy[14], swx[14];
    int n = blockIdx.x, tid = threadIdx.x;
    const float* p = props + n*4;
    if (tid < 28){
        int s = tid % 14;
        bool isx = tid >= 14;
        float c1 = (isx ? p[0] : p[1]) / 511.f;   // nb reorder [1,0,3,2]
        float c2 = (isx ? p[2] : p[3]) / 511.f;
        float t = (float)s / 13.f;
        float v = (c1 + t * (c2 - c1)) * 31.f;
        int v0 = (int)floorf(v);
        v0 = v0 < 0 ? 0 : (v0 > 31 ? 31 : v0);
        int v1i = v0 + 1; if (v1i > 31) v1i = 31;
        float wv = v - (float)v0;
        if (isx){ sx0[s]=v0; sx1[s]=v1i; swx[s]=wv; }
        else    { sy0[s]=v0; sy1[s]=v1i; swy[s]=wv; }
    }
    __syncthreads();
    int c = tid;
    float* outr = pooled + (size_t)n*KFC1 + c*49;
    for (int py = 0; py < 7; py++){
        for (int px = 0; px < 7; px++){
            float mx = -3.402823466e38f;
            #pragma unroll
            for (int dy = 0; dy < 2; dy++){
                #pragma unroll
                for (int dx = 0; dx < 2; dx++){
                    int sy = 2*py + dy, sx = 2*px + dx;
                    int y0 = sy0[sy], y1 = sy1[sy], x0 = sx0[sx], x1 = sx1[sx];
                    float wy = swy[sy], wx = swx[sx];
                    float f00 = feat[(y0*FHW + x0)*CCH + c];
                    float f01 = feat[(y0*FHW + x1)*CCH + c];
                    float f10 = feat[(y1*FHW + x0)*CCH + c];
                    float f11 = feat[(y1*FHW + x1)*CCH + c];
                    float top = f00*(1.f - wx) + f01*wx;
                    float bot = f10*(1.f - wx) + f11*wx;
                    float val = top*(1.f - wy) + bot*wy;
                    mx = fmaxf(mx, val);
                }
            }
            outr[py*7 + px] = mx;
        }
    }
}

// ---------------- tiled GEMM: C = A(MxK,f32) * B(NxK,f32)^T + bias, f64 accum, relu ----------------
__global__ __launch_bounds__(256) void gemm_nt_f(const float* __restrict__ A,
    const float* __restrict__ B, const float* __restrict__ bias,
    float* __restrict__ C, int M, int N, int K){
    __shared__ float As[64][33];
    __shared__ float Bs[64][33];
    int tid = threadIdx.x;
    int tx = tid & 15, ty = tid >> 4;
    int m0 = blockIdx.y*64, n0 = blockIdx.x*64;
    double acc[4][4];
    #pragma unroll
    for (int r = 0; r < 4; r++)
        #pragma unroll
        for (int c = 0; c < 4; c++) acc[r][c] = 0.0;
    for (int k0 = 0; k0 < K; k0 += 32){
        #pragma unroll
        for (int t = tid; t < 2048; t += 256){
            int r = t >> 5, c = t & 31;
            int gm = m0 + r;
            As[r][c] = (gm < M) ? A[(size_t)gm*K + k0 + c] : 0.f;
        }
        #pragma unroll
        for (int t = tid; t < 2048; t += 256){
            int r = t >> 5, c = t & 31;
            int gn = n0 + r;
            Bs[r][c] = (gn < N) ? B[(size_t)gn*K + k0 + c] : 0.f;
        }
        __syncthreads();
        #pragma unroll
        for (int k = 0; k < 32; k++){
            float av[4], bv[4];
            #pragma unroll
            for (int r = 0; r < 4; r++) av[r] = As[ty*4 + r][k];
            #pragma unroll
            for (int c = 0; c < 4; c++) bv[c] = Bs[tx*4 + c][k];
            #pragma unroll
            for (int r = 0; r < 4; r++)
                #pragma unroll
                for (int c = 0; c < 4; c++) acc[r][c] += (double)av[r]*(double)bv[c];
        }
        __syncthreads();
    }
    #pragma unroll
    for (int r = 0; r < 4; r++){
        int gm = m0 + ty*4 + r;
        if (gm >= M) continue;
        #pragma unroll
        for (int c = 0; c < 4; c++){
            int gn = n0 + tx*4 + c;
            double v = acc[r][c] + (double)bias[gn];
            C[(size_t)gm*N + gn] = (float)fmax(v, 0.0);
        }
    }
}

// ---------------- rcnn heads: f64 dot, f32 softmax/decode/clip ----------------
__global__ __launch_bounds__(64) void rcnnhead_k(const float* __restrict__ h2,
    const float* __restrict__ wcls, const float* __restrict__ bcls,
    const float* __restrict__ wreg, const float* __restrict__ breg,
    const float* __restrict__ props,
    float* __restrict__ outLog, float* __restrict__ outDel,
    float* __restrict__ dets, float* __restrict__ scores2){
    int n = blockIdx.x, tid = threadIdx.x;
    const float* hr = h2 + (size_t)n*HID;
    double s[6];
    #pragma unroll
    for (int o = 0; o < 6; o++){
        const float* wrow = (o < 2) ? (wcls + o*HID) : (wreg + (o-2)*HID);
        double a = 0.0;
        for (int k = tid; k < HID; k += 64) a += (double)hr[k] * (double)wrow[k];
        #pragma unroll
        for (int off = 32; off > 0; off >>= 1) a += __shfl_down(a, off, 64);
        s[o] = a;
    }
    if (tid == 0){
        float l0 = (float)(s[0] + (double)bcls[0]), l1 = (float)(s[1] + (double)bcls[1]);
        outLog[n*2 + 0] = l0; outLog[n*2 + 1] = l1;
        float dx = (float)(s[2] + (double)breg[0]), dy = (float)(s[3] + (double)breg[1]);
        float dw = (float)(s[4] + (double)breg[2]), dh = (float)(s[5] + (double)breg[3]);
        outDel[n*4+0] = dx; outDel[n*4+1] = dy; outDel[n*4+2] = dw; outDel[n*4+3] = dh;
        float mm = fmaxf(l0, l1);
        float e0 = expf(l0 - mm), e1 = expf(l1 - mm);
        float sc = e1 / (e0 + e1);
        scores2[n] = sc;
        const float* an = props + n*4;
        float aw = an[2]-an[0]+1.f, ah = an[3]-an[1]+1.f;
        float acx = an[0] + 0.5f*aw, acy = an[1] + 0.5f*ah;
        float pcx = dx*aw + acx, pcy = dy*ah + acy;
        float pw = expf(dw)*aw, ph = expf(dh)*ah;
        float x1 = pcx - 0.5f*pw, y1 = pcy - 0.5f*ph;
        float x2 = pcx + 0.5f*pw, y2 = pcy + 0.5f*ph;
        x1 = fminf(fmaxf(x1, 0.f), 511.f);  y1 = fminf(fmaxf(y1, 0.f), 511.f);
        x2 = fminf(fmaxf(x2, 0.f), 511.f);  y2 = fminf(fmaxf(y2, 0.f), 511.f);
        dets[n*4+0] = x1; dets[n*4+1] = y1; dets[n*4+2] = x2; dets[n*4+3] = y2;
    }
}

// ---------------- final masked gather ----------------
__global__ void finalize_k(const float4* __restrict__ dets, const float* __restrict__ scores2,
                           const int* __restrict__ keep2, const int* __restrict__ cnt2,
                           float* __restrict__ outD, float* __restrict__ outS){
    int j = blockIdx.x*blockDim.x + threadIdx.x;
    if (j >= KP) return;
    int c = *cnt2;
    float m = (j < c) ? 1.f : 0.f;
    int o = keep2[j];
    float4 d = dets[o];
    outD[j*4+0] = d.x*m; outD[j*4+1] = d.y*m; outD[j*4+2] = d.z*m; outD[j*4+3] = d.w*m;
    outS[j] = scores2[o]*m;
}

// ---------------- host ----------------
extern "C" void kernel_launch(void* const* d_in, const int* in_sizes, int n_in,
                              void* d_out, int out_size, void* d_ws, size_t ws_size,
                              hipStream_t stream) {
    const float* x     = (const float*)d_in[0];
    const float* bb_w  = (const float*)d_in[1];
    const float* bb_b  = (const float*)d_in[2];
    const float* rpn_w = (const float*)d_in[3];
    const float* rpn_b = (const float*)d_in[4];
    const float* rcw   = (const float*)d_in[5];
    const float* rcb   = (const float*)d_in[6];
    const float* rrw   = (const float*)d_in[7];
    const float* rrb   = (const float*)d_in[8];
    const float* fc1w  = (const float*)d_in[9];
    const float* fc1b  = (const float*)d_in[10];
    const float* fc2w  = (const float*)d_in[11];
    const float* fc2b  = (const float*)d_in[12];
    const float* clsw  = (const float*)d_in[13];
    const float* clsb  = (const float*)d_in[14];
    const float* regw  = (const float*)d_in[15];
    const float* regb  = (const float*)d_in[16];
    float* out = (float*)d_out;

    char* base = (char*)d_ws;
    size_t off = 0;
    auto carve = [&](size_t bytes) -> void* {
        void* r = base + off;
        off = (off + bytes + 255) & ~(size_t)255;
        return r;
    };
    // persistent
    double* featD   = (double*)carve((size_t)FHW*FHW*CCH*8);
    float*  featF   = (float*)carve((size_t)FHW*FHW*CCH*4);
    double* hD      = (double*)carve((size_t)FHW*FHW*CCH*8);
    double* wbTD    = (double*)carve((size_t)768*CCH*8);
    double* wTD     = (double*)carve((size_t)9*CCH*CCH*8);
    float*  propsF  = (float*)carve((size_t)KP*16);
    int*    cnt1    = (int*)carve(256);
    int*    cnt2    = (int*)carve(256);
    float*  scores2F= (float*)carve((size_t)KP*4);
    float*  dets2F  = (float*)carve((size_t)KP*16);
    int*    order2  = (int*)carve(KP*4);
    float4* sb2F    = (float4*)carve((size_t)KP*16);
    ull*    mask2   = (ull*)carve((size_t)KP*NW2*8);
    int*    keep2   = (int*)carve(KP*4);
    size_t mark = off;
    // phase A (RPN + NMS1)
    float*  boxesF  = (float*)carve((size_t)NAq*16);
    float*  scoresF = (float*)carve((size_t)NAq*4);
    int*    order1  = (int*)carve((size_t)NAq*4);
    float4* sb1F    = (float4*)carve((size_t)NAq*16);
    ull*    mask1   = (ull*)carve((size_t)NAq*NW1*8);
    int*    keep1   = (int*)carve(KP*4);
    // phase B overlaps phase A
    off = mark;
    float*  pooledF = (float*)carve((size_t)KP*KFC1*4);
    float*  h1F     = (float*)carve((size_t)KP*HID*4);
    float*  h2F     = (float*)carve((size_t)KP*HID*4);
    (void)ws_size; (void)in_sizes; (void)n_in; (void)out_size;

    // 1. anchors -> d_out (f32 reference ops)
    anchors_k<<<(NAq+255)/256, 256, 0, stream>>>(out + OFF_ANCH);
    // 2. weight transposes
    transb_k<<<(768*CCH+255)/256, 256, 0, stream>>>(bb_w, wbTD);
    transw_k<<<(9*CCH*CCH+255)/256, 256, 0, stream>>>(rpn_w, wTD);
    // 3. backbone (f64 + f32 copies)
    backbone_k<<<dim3(FHW, FHW), 128, 0, stream>>>(x, wbTD, bb_b, featD, featF);
    // 4. rpn conv (f64)
    rpnconv_k<<<dim3(FHW, FHW), 128, 0, stream>>>(featD, wTD, rpn_b, hD);
    // 5. rpn heads (f64 dot, f32 downstream)
    rpnhead_k<<<FHW*FHW, 64, 0, stream>>>(hD, rcw, rcb, rrw, rrb,
                                          out + OFF_LOGITS, out + OFF_DELTAS, boxesF, scoresF);
    // 6-9. NMS #1 (f32)
    rank_sortf<<<(NAq+255)/256, 256, 0, stream>>>(scoresF, order1, NAq);
    gather_sorted<<<(NAq+255)/256, 256, 0, stream>>>((const float4*)boxesF, order1, sb1F, NAq);
    nms_maskf<<<NAq, 192, 0, stream>>>(sb1F, mask1, NAq, NW1, 0.5f);
    nms_scan1<<<1, 64, 0, stream>>>(mask1, order1, keep1, cnt1, NAq, NW1, KP, 1);
    // 10. proposals
    props_k<<<(KP+255)/256, 256, 0, stream>>>((const float4*)boxesF, keep1,
                                              out + OFF_PROPS, (float4*)propsF);
    // 11. crop + pool (f32)
    croppool_k<<<KP, 128, 0, stream>>>(featF, propsF, pooledF);
    // 12-13. FCs (f64 accum, f32 io)
    gemm_nt_f<<<dim3(HID/64, (KP+63)/64), 256, 0, stream>>>(pooledF, fc1w, fc1b, h1F, KP, HID, KFC1);
    gemm_nt_f<<<dim3(HID/64, (KP+63)/64), 256, 0, stream>>>(h1F, fc2w, fc2b, h2F, KP, HID, HID);
    // 14. rcnn heads
    rcnnhead_k<<<KP, 64, 0, stream>>>(h2F, clsw, clsb, regw, regb, propsF,
                                      out + OFF_RLOG, out + OFF_RDEL, dets2F, scores2F);
    // 15-18. NMS #2 (f32)
    rank_sortf<<<(KP+255)/256, 256, 0, stream>>>(scores2F, order2, KP);
    gather_sorted<<<(KP+255)/256, 256, 0, stream>>>((const float4*)dets2F, order2, sb2F, KP);
    nms_maskf<<<KP, 64, 0, stream>>>(sb2F, mask2, KP, NW2, 0.3f);
    nms_scan1<<<1, 64, 0, stream>>>(mask2, order2, keep2, cnt2, KP, NW2, KP, 0);
    // 19. outputs
    finalize_k<<<(KP+255)/256, 256, 0, stream>>>((const float4*)dets2F, scores2F, keep2, cnt2,
                                                 out + OFF_DETS, out + OFF_SC);
}

// Round 7
// 4598.407 us; speedup vs baseline: 3.8993x; 3.8993x over previous
//
#include <hip/hip_runtime.h>
#include <cstdint>
#include <cstddef>

// ---------------- constants ----------------
#define FHW   32
#define CCH   128
#define NAq   9216
#define NW1   144
#define KP    2000
#define NW2   32
#define HID   1024
#define KFC1  6272

// output offsets (floats)
#define OFF_LOGITS 0
#define OFF_DELTAS 18432
#define OFF_PROPS  55296
#define OFF_ANCH   63296
#define OFF_RLOG   100160
#define OFF_RDEL   104160
#define OFF_DETS   112160
#define OFF_SC     120160

typedef unsigned long long ull;

// f32 anchor, replicating reference op order exactly
__device__ __forceinline__ void anchor_f32(int n, float* a4){
    int a = n % 9, j = (n/9) % FHW, i = n / (9*FHW);
    const float scales[3] = {32.f, 64.f, 128.f};
    const float ratios[3] = {0.5f, 1.f, 2.f};
    float s = scales[a/3], r = ratios[a%3];
    float sq = sqrtf(r);
    float ws = s / sq, hs = s * sq;
    float cx = ((float)j + 0.5f) * 16.f, cy = ((float)i + 0.5f) * 16.f;
    float W2 = ws * 0.5f, H2 = hs * 0.5f;
    a4[0] = cx - W2; a4[1] = cy - H2; a4[2] = cx + W2; a4[3] = cy + H2;
}

__global__ void anchors_k(float* __restrict__ outA){
    int n = blockIdx.x*blockDim.x + threadIdx.x;
    if (n >= NAq) return;
    float a4[4]; anchor_f32(n, a4);
    ((float4*)outA)[n] = make_float4(a4[0], a4[1], a4[2], a4[3]);
}

// ---------------- weight transposes (f32 -> f64) ----------------
__global__ void transb_k(const float* __restrict__ w, double* __restrict__ wT){
    int idx = blockIdx.x*blockDim.x + threadIdx.x;
    if (idx >= CCH*768) return;
    int oc = idx / 768, t = idx % 768;
    wT[t*CCH + oc] = (double)w[idx];
}
__global__ void transw_k(const float* __restrict__ w, double* __restrict__ wT){
    int idx = blockIdx.x*blockDim.x + threadIdx.x;
    if (idx >= CCH*CCH*9) return;
    int oc = idx / (CCH*9);
    int rem = idx % (CCH*9);
    int ic = rem / 9, p = rem % 9;
    wT[(p*CCH + ic)*CCH + oc] = (double)w[idx];
}

// ---------------- backbone conv (f64 accum), writes f64 + f32 copies ----------------
__global__ __launch_bounds__(128) void backbone_k(const float* __restrict__ x,
    const double* __restrict__ wT, const float* __restrict__ b,
    double* __restrict__ featD, float* __restrict__ featF){
    __shared__ double patch[768];
    int j = blockIdx.x, i = blockIdx.y, tid = threadIdx.x;
    for (int t = tid; t < 768; t += 128){
        int ch = t >> 8, rem = t & 255, r = rem >> 4, cl = rem & 15;
        patch[t] = (double)x[ch*512*512 + (i*16 + r)*512 + j*16 + cl];
    }
    __syncthreads();
    double acc = (double)b[tid];
    #pragma unroll 4
    for (int t = 0; t < 768; t++) acc += patch[t] * wT[t*CCH + tid];
    double v = fmax(acc, 0.0);
    featD[(i*FHW + j)*CCH + tid] = v;
    featF[(i*FHW + j)*CCH + tid] = (float)v;
}

// ---------------- rpn 3x3 conv (f64) ----------------
__global__ __launch_bounds__(128) void rpnconv_k(const double* __restrict__ feat,
    const double* __restrict__ wT, const float* __restrict__ b,
    double* __restrict__ h){
    __shared__ double patch[9*CCH];
    int j = blockIdx.x, i = blockIdx.y, tid = threadIdx.x;
    for (int t = tid; t < 9*CCH; t += 128){
        int p = t >> 7, ic = t & 127;
        int y = i + p/3 - 1, xx = j + p%3 - 1;
        patch[t] = (y >= 0 && y < FHW && xx >= 0 && xx < FHW) ? feat[(y*FHW + xx)*CCH + ic] : 0.0;
    }
    __syncthreads();
    double acc = (double)b[tid];
    #pragma unroll 4
    for (int t = 0; t < 9*CCH; t++) acc += patch[t] * wT[t*CCH + tid];
    h[(i*FHW + j)*CCH + tid] = fmax(acc, 0.0);
}

// ---------------- rpn heads: f64 dot, f32 softmax/decode/clip ----------------
__global__ __launch_bounds__(64) void rpnhead_k(const double* __restrict__ h,
    const float* __restrict__ wc, const float* __restrict__ bc,
    const float* __restrict__ wr, const float* __restrict__ br,
    float* __restrict__ outLog, float* __restrict__ outDel,
    float* __restrict__ boxes, float* __restrict__ scores){
    __shared__ double hv[CCH];
    __shared__ double ov[54];
    int pos = blockIdx.x, tid = threadIdx.x;
    hv[tid]      = h[pos*CCH + tid];
    hv[tid + 64] = h[pos*CCH + tid + 64];
    __syncthreads();
    if (tid < 54){
        const float* wrow; double bias;
        if (tid < 18){ wrow = wc + tid*CCH; bias = (double)bc[tid]; }
        else         { wrow = wr + (tid-18)*CCH; bias = (double)br[tid-18]; }
        double acc = bias;
        #pragma unroll 4
        for (int k = 0; k < CCH; k++) acc += hv[k] * (double)wrow[k];
        ov[tid] = acc;
    }
    __syncthreads();
    if (tid < 18) outLog[pos*18 + tid] = (float)ov[tid];
    if (tid < 36) outDel[pos*36 + tid] = (float)ov[18 + tid];
    if (tid < 9){
        int n = pos*9 + tid;
        float l0 = (float)ov[2*tid], l1 = (float)ov[2*tid+1];
        float m = fmaxf(l0, l1);
        float e0 = expf(l0 - m), e1 = expf(l1 - m);
        float s = e1 / (e0 + e1);
        float dx = (float)ov[18+4*tid+0], dy = (float)ov[18+4*tid+1];
        float dw = (float)ov[18+4*tid+2], dh = (float)ov[18+4*tid+3];
        float an[4]; anchor_f32(n, an);
        float aw = an[2] - an[0] + 1.f, ah = an[3] - an[1] + 1.f;
        float acx = an[0] + 0.5f*aw, acy = an[1] + 0.5f*ah;
        float pcx = dx*aw + acx, pcy = dy*ah + acy;
        float pw = expf(dw)*aw, ph = expf(dh)*ah;
        float x1 = pcx - 0.5f*pw, y1 = pcy - 0.5f*ph;
        float x2 = pcx + 0.5f*pw, y2 = pcy + 0.5f*ph;
        x1 = fminf(fmaxf(x1, 0.f), 511.f);  y1 = fminf(fmaxf(y1, 0.f), 511.f);
        x2 = fminf(fmaxf(x2, 0.f), 511.f);  y2 = fminf(fmaxf(y2, 0.f), 511.f);
        ((float4*)boxes)[n] = make_float4(x1, y1, x2, y2);
        scores[n] = s;
    }
}

// ---------------- stable rank sort (desc score, asc index), f32 ----------------
__global__ __launch_bounds__(256) void rank_sortf(const float* __restrict__ sc,
                                                  int* __restrict__ order, int N){
    __shared__ float ss[2048];
    int i = blockIdx.x*blockDim.x + threadIdx.x;
    float mys = (i < N) ? sc[i] : -1e30f;
    int r = 0;
    for (int base = 0; base < N; base += 2048){
        int cnt = min(2048, N - base);
        __syncthreads();
        for (int t = threadIdx.x; t < cnt; t += blockDim.x) ss[t] = sc[base + t];
        __syncthreads();
        for (int j = 0; j < cnt; j++){
            float s = ss[j];
            int jg = base + j;
            r += (s > mys) || (s == mys && jg < i);
        }
    }
    if (i < N) order[r] = i;
}

__global__ void gather_sorted(const float4* __restrict__ boxes, const int* __restrict__ order,
                              float4* __restrict__ sb, int N){
    int r = blockIdx.x*blockDim.x + threadIdx.x;
    if (r < N) sb[r] = boxes[order[r]];
}

// ---------------- IoU suppression bitmask, f32 ----------------
__global__ void nms_maskf(const float4* __restrict__ sb, ull* __restrict__ mask,
                          int N, int Nw, float thr){
    int i = blockIdx.x;
    int w = threadIdx.x;
    if (w >= Nw) return;
    float4 bi = sb[i];
    float areai = (bi.z - bi.x + 1.f) * (bi.w - bi.y + 1.f);
    ull bits = 0;
    int jbase = w*64;
    if (jbase + 63 > i){
        for (int k = 0; k < 64; k++){
            int j = jbase + k;
            if (j <= i || j >= N) continue;
            float4 bj = sb[j];
            float xx1 = fmaxf(bi.x, bj.x), yy1 = fmaxf(bi.y, bj.y);
            float xx2 = fminf(bi.z, bj.z), yy2 = fminf(bi.w, bj.w);
            float iw = fmaxf(xx2 - xx1 + 1.f, 0.f), ih = fmaxf(yy2 - yy1 + 1.f, 0.f);
            float inter = iw * ih;
            float areaj = (bj.z - bj.x + 1.f) * (bj.w - bj.y + 1.f);
            float iou = inter / (areai + areaj - inter);
            if (iou > thr) bits |= (1ull << k);
        }
    }
    mask[(size_t)i*Nw + w] = bits;
}

// ---------------- wave-parallel greedy scan: serial over candidates, parallel OR ----------------
// Single wave (64 threads). Control flow is uniform: the suppression test reads one
// LDS word (broadcast); only the mask-row OR is thread-parallel, barrier-fenced.
__global__ __launch_bounds__(64) void nms_scan_wave(const ull* __restrict__ mask,
                          const int* __restrict__ order,
                          int* __restrict__ keep, int* __restrict__ cntOut,
                          int N, int Nw, int K, int earlyStop){
    __shared__ ull removed[NW1];
    int tid = threadIdx.x;
    for (int t = tid; t < Nw; t += 64) removed[t] = 0ull;
    for (int t = tid; t < K;  t += 64) keep[t] = 0;
    __syncthreads();
    int cnt = 0;
    for (int i = 0; i < N; i++){
        int iw = i >> 6, ib = i & 63;
        if ((removed[iw] >> ib) & 1ull) continue;    // uniform broadcast read
        if (tid == 0 && cnt < K) keep[cnt] = order[i];
        cnt++;
        if (earlyStop && cnt >= K) break;
        const ull* mrow = mask + (size_t)i*Nw;
        __syncthreads();
        for (int w = iw + tid; w < Nw; w += 64) removed[w] |= mrow[w];
        __syncthreads();
    }
    if (tid == 0) *cntOut = cnt;
}

// ---------------- gather proposals ----------------
__global__ void props_k(const float4* __restrict__ boxes, const int* __restrict__ keep1,
                        float* __restrict__ outP, float4* __restrict__ propsWs){
    int j = blockIdx.x*blockDim.x + threadIdx.x;
    if (j >= KP) return;
    float4 b = boxes[keep1[j]];
    ((float4*)outP)[j] = b;
    propsWs[j] = b;
}

// ---------------- crop_resize(14) + 2x2 maxpool, f32 ----------------
__global__ __launch_bounds__(128) void croppool_k(const float* __restrict__ feat,
    const float* __restrict__ props, float* __restrict__ pooled){
    __shared__ int   sy0[14], sy1[14], sx0[14], sx1[14];
    __shared__ float swy[14], swx[14];
    int n = blockIdx.x, tid = threadIdx.x;
    const float* p = props + n*4;
    if (tid < 28){
        int s = tid % 14;
        bool isx = tid >= 14;
        float c1 = (isx ? p[0] : p[1]) / 511.f;   // nb reorder [1,0,3,2]
        float c2 = (isx ? p[2] : p[3]) / 511.f;
        float t = (float)s / 13.f;
        float v = (c1 + t * (c2 - c1)) * 31.f;
        int v0 = (int)floorf(v);
        v0 = v0 < 0 ? 0 : (v0 > 31 ? 31 : v0);
        int v1i = v0 + 1; if (v1i > 31) v1i = 31;
        float wv = v - (float)v0;
        if (isx){ sx0[s]=v0; sx1[s]=v1i; swx[s]=wv; }
        else    { sy0[s]=v0; sy1[s]=v1i; swy[s]=wv; }
    }
    __syncthreads();
    int c = tid;
    float* outr = pooled + (size_t)n*KFC1 + c*49;
    for (int py = 0; py < 7; py++){
        for (int px = 0; px < 7; px++){
            float mx = -3.402823466e38f;
            #pragma unroll
            for (int dy = 0; dy < 2; dy++){
                #pragma unroll
                for (int dx = 0; dx < 2; dx++){
                    int sy = 2*py + dy, sx = 2*px + dx;
                    int y0 = sy0[sy], y1 = sy1[sy], x0 = sx0[sx], x1 = sx1[sx];
                    float wy = swy[sy], wx = swx[sx];
                    float f00 = feat[(y0*FHW + x0)*CCH + c];
                    float f01 = feat[(y0*FHW + x1)*CCH + c];
                    float f10 = feat[(y1*FHW + x0)*CCH + c];
                    float f11 = feat[(y1*FHW + x1)*CCH + c];
                    float top = f00*(1.f - wx) + f01*wx;
                    float bot = f10*(1.f - wx) + f11*wx;
                    float val = top*(1.f - wy) + bot*wy;
                    mx = fmaxf(mx, val);
                }
            }
            outr[py*7 + px] = mx;
        }
    }
}

// ---------------- tiled GEMM: C = A(MxK,f32) * B(NxK,f32)^T + bias, f64 accum, relu ----------------
__global__ __launch_bounds__(256) void gemm_nt_f(const float* __restrict__ A,
    const float* __restrict__ B, const float* __restrict__ bias,
    float* __restrict__ C, int M, int N, int K){
    __shared__ float As[64][33];
    __shared__ float Bs[64][33];
    int tid = threadIdx.x;
    int tx = tid & 15, ty = tid >> 4;
    int m0 = blockIdx.y*64, n0 = blockIdx.x*64;
    double acc[4][4];
    #pragma unroll
    for (int r = 0; r < 4; r++)
        #pragma unroll
        for (int c = 0; c < 4; c++) acc[r][c] = 0.0;
    for (int k0 = 0; k0 < K; k0 += 32){
        #pragma unroll
        for (int t = tid; t < 2048; t += 256){
            int r = t >> 5, c = t & 31;
            int gm = m0 + r;
            As[r][c] = (gm < M) ? A[(size_t)gm*K + k0 + c] : 0.f;
        }
        #pragma unroll
        for (int t = tid; t < 2048; t += 256){
            int r = t >> 5, c = t & 31;
            int gn = n0 + r;
            Bs[r][c] = (gn < N) ? B[(size_t)gn*K + k0 + c] : 0.f;
        }
        __syncthreads();
        #pragma unroll
        for (int k = 0; k < 32; k++){
            float av[4], bv[4];
            #pragma unroll
            for (int r = 0; r < 4; r++) av[r] = As[ty*4 + r][k];
            #pragma unroll
            for (int c = 0; c < 4; c++) bv[c] = Bs[tx*4 + c][k];
            #pragma unroll
            for (int r = 0; r < 4; r++)
                #pragma unroll
                for (int c = 0; c < 4; c++) acc[r][c] += (double)av[r]*(double)bv[c];
        }
        __syncthreads();
    }
    #pragma unroll
    for (int r = 0; r < 4; r++){
        int gm = m0 + ty*4 + r;
        if (gm >= M) continue;
        #pragma unroll
        for (int c = 0; c < 4; c++){
            int gn = n0 + tx*4 + c;
            double v = acc[r][c] + (double)bias[gn];
            C[(size_t)gm*N + gn] = (float)fmax(v, 0.0);
        }
    }
}

// ---------------- rcnn heads: f64 dot, f32 softmax/decode/clip ----------------
__global__ __launch_bounds__(64) void rcnnhead_k(const float* __restrict__ h2,
    const float* __restrict__ wcls, const float* __restrict__ bcls,
    const float* __restrict__ wreg, const float* __restrict__ breg,
    const float* __restrict__ props,
    float* __restrict__ outLog, float* __restrict__ outDel,
    float* __restrict__ dets, float* __restrict__ scores2){
    int n = blockIdx.x, tid = threadIdx.x;
    const float* hr = h2 + (size_t)n*HID;
    double s[6];
    #pragma unroll
    for (int o = 0; o < 6; o++){
        const float* wrow = (o < 2) ? (wcls + o*HID) : (wreg + (o-2)*HID);
        double a = 0.0;
        for (int k = tid; k < HID; k += 64) a += (double)hr[k] * (double)wrow[k];
        #pragma unroll
        for (int off = 32; off > 0; off >>= 1) a += __shfl_down(a, off, 64);
        s[o] = a;
    }
    if (tid == 0){
        float l0 = (float)(s[0] + (double)bcls[0]), l1 = (float)(s[1] + (double)bcls[1]);
        outLog[n*2 + 0] = l0; outLog[n*2 + 1] = l1;
        float dx = (float)(s[2] + (double)breg[0]), dy = (float)(s[3] + (double)breg[1]);
        float dw = (float)(s[4] + (double)breg[2]), dh = (float)(s[5] + (double)breg[3]);
        outDel[n*4+0] = dx; outDel[n*4+1] = dy; outDel[n*4+2] = dw; outDel[n*4+3] = dh;
        float mm = fmaxf(l0, l1);
        float e0 = expf(l0 - mm), e1 = expf(l1 - mm);
        float sc = e1 / (e0 + e1);
        scores2[n] = sc;
        const float* an = props + n*4;
        float aw = an[2]-an[0]+1.f, ah = an[3]-an[1]+1.f;
        float acx = an[0] + 0.5f*aw, acy = an[1] + 0.5f*ah;
        float pcx = dx*aw + acx, pcy = dy*ah + acy;
        float pw = expf(dw)*aw, ph = expf(dh)*ah;
        float x1 = pcx - 0.5f*pw, y1 = pcy - 0.5f*ph;
        float x2 = pcx + 0.5f*pw, y2 = pcy + 0.5f*ph;
        x1 = fminf(fmaxf(x1, 0.f), 511.f);  y1 = fminf(fmaxf(y1, 0.f), 511.f);
        x2 = fminf(fmaxf(x2, 0.f), 511.f);  y2 = fminf(fmaxf(y2, 0.f), 511.f);
        dets[n*4+0] = x1; dets[n*4+1] = y1; dets[n*4+2] = x2; dets[n*4+3] = y2;
    }
}

// ---------------- final masked gather ----------------
__global__ void finalize_k(const float4* __restrict__ dets, const float* __restrict__ scores2,
                           const int* __restrict__ keep2, const int* __restrict__ cnt2,
                           float* __restrict__ outD, float* __restrict__ outS){
    int j = blockIdx.x*blockDim.x + threadIdx.x;
    if (j >= KP) return;
    int c = *cnt2;
    float m = (j < c) ? 1.f : 0.f;
    int o = keep2[j];
    float4 d = dets[o];
    outD[j*4+0] = d.x*m; outD[j*4+1] = d.y*m; outD[j*4+2] = d.z*m; outD[j*4+3] = d.w*m;
    outS[j] = scores2[o]*m;
}

// ---------------- host ----------------
extern "C" void kernel_launch(void* const* d_in, const int* in_sizes, int n_in,
                              void* d_out, int out_size, void* d_ws, size_t ws_size,
                              hipStream_t stream) {
    const float* x     = (const float*)d_in[0];
    const float* bb_w  = (const float*)d_in[1];
    const float* bb_b  = (const float*)d_in[2];
    const float* rpn_w = (const float*)d_in[3];
    const float* rpn_b = (const float*)d_in[4];
    const float* rcw   = (const float*)d_in[5];
    const float* rcb   = (const float*)d_in[6];
    const float* rrw   = (const float*)d_in[7];
    const float* rrb   = (const float*)d_in[8];
    const float* fc1w  = (const float*)d_in[9];
    const float* fc1b  = (const float*)d_in[10];
    const float* fc2w  = (const float*)d_in[11];
    const float* fc2b  = (const float*)d_in[12];
    const float* clsw  = (const float*)d_in[13];
    const float* clsb  = (const float*)d_in[14];
    const float* regw  = (const float*)d_in[15];
    const float* regb  = (const float*)d_in[16];
    float* out = (float*)d_out;

    char* base = (char*)d_ws;
    size_t off = 0;
    auto carve = [&](size_t bytes) -> void* {
        void* r = base + off;
        off = (off + bytes + 255) & ~(size_t)255;
        return r;
    };
    // persistent
    double* featD   = (double*)carve((size_t)FHW*FHW*CCH*8);
    float*  featF   = (float*)carve((size_t)FHW*FHW*CCH*4);
    double* hD      = (double*)carve((size_t)FHW*FHW*CCH*8);
    double* wbTD    = (double*)carve((size_t)768*CCH*8);
    double* wTD     = (double*)carve((size_t)9*CCH*CCH*8);
    float*  propsF  = (float*)carve((size_t)KP*16);
    int*    cnt1    = (int*)carve(256);
    int*    cnt2    = (int*)carve(256);
    float*  scores2F= (float*)carve((size_t)KP*4);
    float*  dets2F  = (float*)carve((size_t)KP*16);
    int*    order2  = (int*)carve(KP*4);
    float4* sb2F    = (float4*)carve((size_t)KP*16);
    ull*    mask2   = (ull*)carve((size_t)KP*NW2*8);
    int*    keep2   = (int*)carve(KP*4);
    size_t mark = off;
    // phase A (RPN + NMS1)
    float*  boxesF  = (float*)carve((size_t)NAq*16);
    float*  scoresF = (float*)carve((size_t)NAq*4);
    int*    order1  = (int*)carve((size_t)NAq*4);
    float4* sb1F    = (float4*)carve((size_t)NAq*16);
    ull*    mask1   = (ull*)carve((size_t)NAq*NW1*8);
    int*    keep1   = (int*)carve(KP*4);
    // phase B overlaps phase A
    off = mark;
    float*  pooledF = (float*)carve((size_t)KP*KFC1*4);
    float*  h1F     = (float*)carve((size_t)KP*HID*4);
    float*  h2F     = (float*)carve((size_t)KP*HID*4);
    (void)ws_size; (void)in_sizes; (void)n_in; (void)out_size;

    // 1. anchors -> d_out (f32 reference ops)
    anchors_k<<<(NAq+255)/256, 256, 0, stream>>>(out + OFF_ANCH);
    // 2. weight transposes
    transb_k<<<(768*CCH+255)/256, 256, 0, stream>>>(bb_w, wbTD);
    transw_k<<<(9*CCH*CCH+255)/256, 256, 0, stream>>>(rpn_w, wTD);
    // 3. backbone (f64 + f32 copies)
    backbone_k<<<dim3(FHW, FHW), 128, 0, stream>>>(x, wbTD, bb_b, featD, featF);
    // 4. rpn conv (f64)
    rpnconv_k<<<dim3(FHW, FHW), 128, 0, stream>>>(featD, wTD, rpn_b, hD);
    // 5. rpn heads (f64 dot, f32 downstream)
    rpnhead_k<<<FHW*FHW, 64, 0, stream>>>(hD, rcw, rcb, rrw, rrb,
                                          out + OFF_LOGITS, out + OFF_DELTAS, boxesF, scoresF);
    // 6-9. NMS #1 (f32)
    rank_sortf<<<(NAq+255)/256, 256, 0, stream>>>(scoresF, order1, NAq);
    gather_sorted<<<(NAq+255)/256, 256, 0, stream>>>((const float4*)boxesF, order1, sb1F, NAq);
    nms_maskf<<<NAq, 192, 0, stream>>>(sb1F, mask1, NAq, NW1, 0.5f);
    nms_scan_wave<<<1, 64, 0, stream>>>(mask1, order1, keep1, cnt1, NAq, NW1, KP, 1);
    // 10. proposals
    props_k<<<(KP+255)/256, 256, 0, stream>>>((const float4*)boxesF, keep1,
                                              out + OFF_PROPS, (float4*)propsF);
    // 11. crop + pool (f32)
    croppool_k<<<KP, 128, 0, stream>>>(featF, propsF, pooledF);
    // 12-13. FCs (f64 accum, f32 io)
    gemm_nt_f<<<dim3(HID/64, (KP+63)/64), 256, 0, stream>>>(pooledF, fc1w, fc1b, h1F, KP, HID, KFC1);
    gemm_nt_f<<<dim3(HID/64, (KP+63)/64), 256, 0, stream>>>(h1F, fc2w, fc2b, h2F, KP, HID, HID);
    // 14. rcnn heads
    rcnnhead_k<<<KP, 64, 0, stream>>>(h2F, clsw, clsb, regw, regb, propsF,
                                      out + OFF_RLOG, out + OFF_RDEL, dets2F, scores2F);
    // 15-18. NMS #2 (f32)
    rank_sortf<<<(KP+255)/256, 256, 0, stream>>>(scores2F, order2, KP);
    gather_sorted<<<(KP+255)/256, 256, 0, stream>>>((const float4*)dets2F, order2, sb2F, KP);
    nms_maskf<<<KP, 64, 0, stream>>>(sb2F, mask2, KP, NW2, 0.3f);
    nms_scan_wave<<<1, 64, 0, stream>>>(mask2, order2, keep2, cnt2, KP, NW2, KP, 0);
    // 19. outputs
    finalize_k<<<(KP+255)/256, 256, 0, stream>>>((const float4*)dets2F, scores2F, keep2, cnt2,
                                                 out + OFF_DETS, out + OFF_SC);
}

// Round 8
// 4019.609 us; speedup vs baseline: 4.4608x; 1.1440x over previous
//
#include <hip/hip_runtime.h>
#include <cstdint>
#include <cstddef>

// ---------------- constants ----------------
#define FHW   32
#define CCH   128
#define NAq   9216
#define NW1   144
#define KP    2000
#define NW2   32
#define HID   1024
#define KFC1  6272

// output offsets (floats)
#define OFF_LOGITS 0
#define OFF_DELTAS 18432
#define OFF_PROPS  55296
#define OFF_ANCH   63296
#define OFF_RLOG   100160
#define OFF_RDEL   104160
#define OFF_DETS   112160
#define OFF_SC     120160

typedef unsigned long long ull;

// f32 anchor, replicating reference op order exactly
__device__ __forceinline__ void anchor_f32(int n, float* a4){
    int a = n % 9, j = (n/9) % FHW, i = n / (9*FHW);
    const float scales[3] = {32.f, 64.f, 128.f};
    const float ratios[3] = {0.5f, 1.f, 2.f};
    float s = scales[a/3], r = ratios[a%3];
    float sq = sqrtf(r);
    float ws = s / sq, hs = s * sq;
    float cx = ((float)j + 0.5f) * 16.f, cy = ((float)i + 0.5f) * 16.f;
    float W2 = ws * 0.5f, H2 = hs * 0.5f;
    a4[0] = cx - W2; a4[1] = cy - H2; a4[2] = cx + W2; a4[3] = cy + H2;
}

__global__ void anchors_k(float* __restrict__ outA){
    int n = blockIdx.x*blockDim.x + threadIdx.x;
    if (n >= NAq) return;
    float a4[4]; anchor_f32(n, a4);
    ((float4*)outA)[n] = make_float4(a4[0], a4[1], a4[2], a4[3]);
}

// ---------------- weight transposes (f32 -> f64) ----------------
__global__ void transb_k(const float* __restrict__ w, double* __restrict__ wT){
    int idx = blockIdx.x*blockDim.x + threadIdx.x;
    if (idx >= CCH*768) return;
    int oc = idx / 768, t = idx % 768;
    wT[t*CCH + oc] = (double)w[idx];
}
__global__ void transw_k(const float* __restrict__ w, double* __restrict__ wT){
    int idx = blockIdx.x*blockDim.x + threadIdx.x;
    if (idx >= CCH*CCH*9) return;
    int oc = idx / (CCH*9);
    int rem = idx % (CCH*9);
    int ic = rem / 9, p = rem % 9;
    wT[(p*CCH + ic)*CCH + oc] = (double)w[idx];
}

// ---------------- backbone conv (f64 accum), writes f64 + f32 copies ----------------
__global__ __launch_bounds__(128) void backbone_k(const float* __restrict__ x,
    const double* __restrict__ wT, const float* __restrict__ b,
    double* __restrict__ featD, float* __restrict__ featF){
    __shared__ double patch[768];
    int j = blockIdx.x, i = blockIdx.y, tid = threadIdx.x;
    for (int t = tid; t < 768; t += 128){
        int ch = t >> 8, rem = t & 255, r = rem >> 4, cl = rem & 15;
        patch[t] = (double)x[ch*512*512 + (i*16 + r)*512 + j*16 + cl];
    }
    __syncthreads();
    double acc = (double)b[tid];
    #pragma unroll 4
    for (int t = 0; t < 768; t++) acc += patch[t] * wT[t*CCH + tid];
    double v = fmax(acc, 0.0);
    featD[(i*FHW + j)*CCH + tid] = v;
    featF[(i*FHW + j)*CCH + tid] = (float)v;
}

// ---------------- rpn 3x3 conv (f64) ----------------
__global__ __launch_bounds__(128) void rpnconv_k(const double* __restrict__ feat,
    const double* __restrict__ wT, const float* __restrict__ b,
    double* __restrict__ h){
    __shared__ double patch[9*CCH];
    int j = blockIdx.x, i = blockIdx.y, tid = threadIdx.x;
    for (int t = tid; t < 9*CCH; t += 128){
        int p = t >> 7, ic = t & 127;
        int y = i + p/3 - 1, xx = j + p%3 - 1;
        patch[t] = (y >= 0 && y < FHW && xx >= 0 && xx < FHW) ? feat[(y*FHW + xx)*CCH + ic] : 0.0;
    }
    __syncthreads();
    double acc = (double)b[tid];
    #pragma unroll 4
    for (int t = 0; t < 9*CCH; t++) acc += patch[t] * wT[t*CCH + tid];
    h[(i*FHW + j)*CCH + tid] = fmax(acc, 0.0);
}

// ---------------- rpn heads: f64 dot, f32 softmax/decode/clip ----------------
__global__ __launch_bounds__(64) void rpnhead_k(const double* __restrict__ h,
    const float* __restrict__ wc, const float* __restrict__ bc,
    const float* __restrict__ wr, const float* __restrict__ br,
    float* __restrict__ outLog, float* __restrict__ outDel,
    float* __restrict__ boxes, float* __restrict__ scores){
    __shared__ double hv[CCH];
    __shared__ double ov[54];
    int pos = blockIdx.x, tid = threadIdx.x;
    hv[tid]      = h[pos*CCH + tid];
    hv[tid + 64] = h[pos*CCH + tid + 64];
    __syncthreads();
    if (tid < 54){
        const float* wrow; double bias;
        if (tid < 18){ wrow = wc + tid*CCH; bias = (double)bc[tid]; }
        else         { wrow = wr + (tid-18)*CCH; bias = (double)br[tid-18]; }
        double acc = bias;
        #pragma unroll 4
        for (int k = 0; k < CCH; k++) acc += hv[k] * (double)wrow[k];
        ov[tid] = acc;
    }
    __syncthreads();
    if (tid < 18) outLog[pos*18 + tid] = (float)ov[tid];
    if (tid < 36) outDel[pos*36 + tid] = (float)ov[18 + tid];
    if (tid < 9){
        int n = pos*9 + tid;
        float l0 = (float)ov[2*tid], l1 = (float)ov[2*tid+1];
        float m = fmaxf(l0, l1);
        float e0 = expf(l0 - m), e1 = expf(l1 - m);
        float s = e1 / (e0 + e1);
        float dx = (float)ov[18+4*tid+0], dy = (float)ov[18+4*tid+1];
        float dw = (float)ov[18+4*tid+2], dh = (float)ov[18+4*tid+3];
        float an[4]; anchor_f32(n, an);
        float aw = an[2] - an[0] + 1.f, ah = an[3] - an[1] + 1.f;
        float acx = an[0] + 0.5f*aw, acy = an[1] + 0.5f*ah;
        float pcx = dx*aw + acx, pcy = dy*ah + acy;
        float pw = expf(dw)*aw, ph = expf(dh)*ah;
        float x1 = pcx - 0.5f*pw, y1 = pcy - 0.5f*ph;
        float x2 = pcx + 0.5f*pw, y2 = pcy + 0.5f*ph;
        x1 = fminf(fmaxf(x1, 0.f), 511.f);  y1 = fminf(fmaxf(y1, 0.f), 511.f);
        x2 = fminf(fmaxf(x2, 0.f), 511.f);  y2 = fminf(fmaxf(y2, 0.f), 511.f);
        ((float4*)boxes)[n] = make_float4(x1, y1, x2, y2);
        scores[n] = s;
    }
}

// ---------------- stable rank sort (desc score, asc index), f32 ----------------
__global__ __launch_bounds__(256) void rank_sortf(const float* __restrict__ sc,
                                                  int* __restrict__ order, int N){
    __shared__ float ss[2048];
    int i = blockIdx.x*blockDim.x + threadIdx.x;
    float mys = (i < N) ? sc[i] : -1e30f;
    int r = 0;
    for (int base = 0; base < N; base += 2048){
        int cnt = min(2048, N - base);
        __syncthreads();
        for (int t = threadIdx.x; t < cnt; t += blockDim.x) ss[t] = sc[base + t];
        __syncthreads();
        for (int j = 0; j < cnt; j++){
            float s = ss[j];
            int jg = base + j;
            r += (s > mys) || (s == mys && jg < i);
        }
    }
    if (i < N) order[r] = i;
}

__global__ void gather_sorted(const float4* __restrict__ boxes, const int* __restrict__ order,
                              float4* __restrict__ sb, int N){
    int r = blockIdx.x*blockDim.x + threadIdx.x;
    if (r < N) sb[r] = boxes[order[r]];
}

// ---------------- IoU suppression bitmask via ballot: 1 wave per box i ----------------
// Lane k tests candidate j = w*64+k -> __ballot gives the 64-bit word directly.
// Words w < i/64 are never read by the scan (row i only consulted for w >= chunk(i)),
// so start at w0 = i>>6. Loads of sb[j] are lane-coalesced.
__global__ __launch_bounds__(64) void nms_maskb(const float4* __restrict__ sb,
                          ull* __restrict__ mask, int N, int Nw, float thr){
    int i = blockIdx.x;
    int lane = threadIdx.x;
    float4 bi = sb[i];
    float areai = (bi.z - bi.x + 1.f) * (bi.w - bi.y + 1.f);
    int w0 = i >> 6;
    for (int w = w0; w < Nw; w++){
        int j = w*64 + lane;
        bool sup = false;
        if (j < N && j > i){
            float4 bj = sb[j];
            float xx1 = fmaxf(bi.x, bj.x), yy1 = fmaxf(bi.y, bj.y);
            float xx2 = fminf(bi.z, bj.z), yy2 = fminf(bi.w, bj.w);
            float iw = fmaxf(xx2 - xx1 + 1.f, 0.f), ih = fmaxf(yy2 - yy1 + 1.f, 0.f);
            float inter = iw * ih;
            float areaj = (bj.z - bj.x + 1.f) * (bj.w - bj.y + 1.f);
            float iou = inter / (areai + areaj - inter);
            sup = iou > thr;
        }
        ull bits = __ballot(sup);
        if (lane == 0) mask[(size_t)i*Nw + w] = bits;
    }
}

// ---------------- chunk-deferred greedy scan (1 wave) ----------------
// Per 64-candidate chunk: preload diagonal 64x64 mask block to LDS (one coalesced
// load), resolve intra-chunk suppression serially from LDS, then batch-OR the full
// mask rows of this chunk's kept candidates into removed[] in parallel.
// Greedy semantics identical: prior chunks via removed[iw], intra-chunk via diag[b].
__global__ __launch_bounds__(64) void nms_scan2(const ull* __restrict__ mask,
                          const int* __restrict__ order,
                          int* __restrict__ keep, int* __restrict__ cntOut,
                          int N, int Nw, int K, int earlyStop){
    __shared__ ull removed[NW1];
    __shared__ ull diag[64];
    __shared__ int keptIdx[64];
    int tid = threadIdx.x;
    for (int t = tid; t < Nw; t += 64) removed[t] = 0ull;
    for (int t = tid; t < K;  t += 64) keep[t] = 0;
    __syncthreads();
    int cnt = 0;
    bool done = false;
    for (int iw = 0; iw < Nw && !done; ++iw){
        int i0 = iw << 6;
        int lim = N - i0; if (lim > 64) lim = 64;
        if (tid < lim) diag[tid] = mask[(size_t)(i0 + tid)*Nw + iw];
        __syncthreads();
        ull pending = ~removed[iw];
        if (lim < 64) pending &= (1ull << lim) - 1ull;
        int nk = 0;
        while (pending){
            int b = __builtin_ctzll(pending);
            if (tid == 0 && cnt < K) keep[cnt] = order[i0 + b];
            keptIdx[nk] = i0 + b;          // same value from every lane — benign
            nk++; cnt++;
            if (earlyStop && cnt >= K){ done = true; break; }
            pending &= ~(1ull << b);
            pending &= ~diag[b];           // LDS broadcast read
        }
        if (done) break;
        __syncthreads();
        for (int r = 0; r < nk; r++){
            const ull* mrow = mask + (size_t)keptIdx[r]*Nw;
            for (int w = iw + 1 + tid; w < Nw; w += 64) removed[w] |= mrow[w];
        }
        __syncthreads();
    }
    if (tid == 0) *cntOut = cnt;
}

// ---------------- gather proposals ----------------
__global__ void props_k(const float4* __restrict__ boxes, const int* __restrict__ keep1,
                        float* __restrict__ outP, float4* __restrict__ propsWs){
    int j = blockIdx.x*blockDim.x + threadIdx.x;
    if (j >= KP) return;
    float4 b = boxes[keep1[j]];
    ((float4*)outP)[j] = b;
    propsWs[j] = b;
}

// ---------------- crop_resize(14) + 2x2 maxpool, f32 ----------------
__global__ __launch_bounds__(128) void croppool_k(const float* __restrict__ feat,
    const float* __restrict__ props, float* __restrict__ pooled){
    __shared__ int   sy0[14], sy1[14], sx0[14], sx1[14];
    __shared__ float swy[14], swx[14];
    int n = blockIdx.x, tid = threadIdx.x;
    const float* p = props + n*4;
    if (tid < 28){
        int s = tid % 14;
        bool isx = tid >= 14;
        float c1 = (isx ? p[0] : p[1]) / 511.f;   // nb reorder [1,0,3,2]
        float c2 = (isx ? p[2] : p[3]) / 511.f;
        float t = (float)s / 13.f;
        float v = (c1 + t * (c2 - c1)) * 31.f;
        int v0 = (int)floorf(v);
        v0 = v0 < 0 ? 0 : (v0 > 31 ? 31 : v0);
        int v1i = v0 + 1; if (v1i > 31) v1i = 31;
        float wv = v - (float)v0;
        if (isx){ sx0[s]=v0; sx1[s]=v1i; swx[s]=wv; }
        else    { sy0[s]=v0; sy1[s]=v1i; swy[s]=wv; }
    }
    __syncthreads();
    int c = tid;
    float* outr = pooled + (size_t)n*KFC1 + c*49;
    for (int py = 0; py < 7; py++){
        for (int px = 0; px < 7; px++){
            float mx = -3.402823466e38f;
            #pragma unroll
            for (int dy = 0; dy < 2; dy++){
                #pragma unroll
                for (int dx = 0; dx < 2; dx++){
                    int sy = 2*py + dy, sx = 2*px + dx;
                    int y0 = sy0[sy], y1 = sy1[sy], x0 = sx0[sx], x1 = sx1[sx];
                    float wy = swy[sy], wx = swx[sx];
                    float f00 = feat[(y0*FHW + x0)*CCH + c];
                    float f01 = feat[(y0*FHW + x1)*CCH + c];
                    float f10 = feat[(y1*FHW + x0)*CCH + c];
                    float f11 = feat[(y1*FHW + x1)*CCH + c];
                    float top = f00*(1.f - wx) + f01*wx;
                    float bot = f10*(1.f - wx) + f11*wx;
                    float val = top*(1.f - wy) + bot*wy;
                    mx = fmaxf(mx, val);
                }
            }
            outr[py*7 + px] = mx;
        }
    }
}

// ---------------- tiled GEMM: C = A(MxK,f32) * B(NxK,f32)^T + bias, f64 accum, relu ----------------
__global__ __launch_bounds__(256) void gemm_nt_f(const float* __restrict__ A,
    const float* __restrict__ B, const float* __restrict__ bias,
    float* __restrict__ C, int M, int N, int K){
    __shared__ float As[64][33];
    __shared__ float Bs[64][33];
    int tid = threadIdx.x;
    int tx = tid & 15, ty = tid >> 4;
    int m0 = blockIdx.y*64, n0 = blockIdx.x*64;
    double acc[4][4];
    #pragma unroll
    for (int r = 0; r < 4; r++)
        #pragma unroll
        for (int c = 0; c < 4; c++) acc[r][c] = 0.0;
    for (int k0 = 0; k0 < K; k0 += 32){
        #pragma unroll
        for (int t = tid; t < 2048; t += 256){
            int r = t >> 5, c = t & 31;
            int gm = m0 + r;
            As[r][c] = (gm < M) ? A[(size_t)gm*K + k0 + c] : 0.f;
        }
        #pragma unroll
        for (int t = tid; t < 2048; t += 256){
            int r = t >> 5, c = t & 31;
            int gn = n0 + r;
            Bs[r][c] = (gn < N) ? B[(size_t)gn*K + k0 + c] : 0.f;
        }
        __syncthreads();
        #pragma unroll
        for (int k = 0; k < 32; k++){
            float av[4], bv[4];
            #pragma unroll
            for (int r = 0; r < 4; r++) av[r] = As[ty*4 + r][k];
            #pragma unroll
            for (int c = 0; c < 4; c++) bv[c] = Bs[tx*4 + c][k];
            #pragma unroll
            for (int r = 0; r < 4; r++)
                #pragma unroll
                for (int c = 0; c < 4; c++) acc[r][c] += (double)av[r]*(double)bv[c];
        }
        __syncthreads();
    }
    #pragma unroll
    for (int r = 0; r < 4; r++){
        int gm = m0 + ty*4 + r;
        if (gm >= M) continue;
        #pragma unroll
        for (int c = 0; c < 4; c++){
            int gn = n0 + tx*4 + c;
            double v = acc[r][c] + (double)bias[gn];
            C[(size_t)gm*N + gn] = (float)fmax(v, 0.0);
        }
    }
}

// ---------------- rcnn heads: f64 dot, f32 softmax/decode/clip ----------------
__global__ __launch_bounds__(64) void rcnnhead_k(const float* __restrict__ h2,
    const float* __restrict__ wcls, const float* __restrict__ bcls,
    const float* __restrict__ wreg, const float* __restrict__ breg,
    const float* __restrict__ props,
    float* __restrict__ outLog, float* __restrict__ outDel,
    float* __restrict__ dets, float* __restrict__ scores2){
    int n = blockIdx.x, tid = threadIdx.x;
    const float* hr = h2 + (size_t)n*HID;
    double s[6];
    #pragma unroll
    for (int o = 0; o < 6; o++){
        const float* wrow = (o < 2) ? (wcls + o*HID) : (wreg + (o-2)*HID);
        double a = 0.0;
        for (int k = tid; k < HID; k += 64) a += (double)hr[k] * (double)wrow[k];
        #pragma unroll
        for (int off = 32; off > 0; off >>= 1) a += __shfl_down(a, off, 64);
        s[o] = a;
    }
    if (tid == 0){
        float l0 = (float)(s[0] + (double)bcls[0]), l1 = (float)(s[1] + (double)bcls[1]);
        outLog[n*2 + 0] = l0; outLog[n*2 + 1] = l1;
        float dx = (float)(s[2] + (double)breg[0]), dy = (float)(s[3] + (double)breg[1]);
        float dw = (float)(s[4] + (double)breg[2]), dh = (float)(s[5] + (double)breg[3]);
        outDel[n*4+0] = dx; outDel[n*4+1] = dy; outDel[n*4+2] = dw; outDel[n*4+3] = dh;
        float mm = fmaxf(l0, l1);
        float e0 = expf(l0 - mm), e1 = expf(l1 - mm);
        float sc = e1 / (e0 + e1);
        scores2[n] = sc;
        const float* an = props + n*4;
        float aw = an[2]-an[0]+1.f, ah = an[3]-an[1]+1.f;
        float acx = an[0] + 0.5f*aw, acy = an[1] + 0.5f*ah;
        float pcx = dx*aw + acx, pcy = dy*ah + acy;
        float pw = expf(dw)*aw, ph = expf(dh)*ah;
        float x1 = pcx - 0.5f*pw, y1 = pcy - 0.5f*ph;
        float x2 = pcx + 0.5f*pw, y2 = pcy + 0.5f*ph;
        x1 = fminf(fmaxf(x1, 0.f), 511.f);  y1 = fminf(fmaxf(y1, 0.f), 511.f);
        x2 = fminf(fmaxf(x2, 0.f), 511.f);  y2 = fminf(fmaxf(y2, 0.f), 511.f);
        dets[n*4+0] = x1; dets[n*4+1] = y1; dets[n*4+2] = x2; dets[n*4+3] = y2;
    }
}

// ---------------- final masked gather ----------------
__global__ void finalize_k(const float4* __restrict__ dets, const float* __restrict__ scores2,
                           const int* __restrict__ keep2, const int* __restrict__ cnt2,
                           float* __restrict__ outD, float* __restrict__ outS){
    int j = blockIdx.x*blockDim.x + threadIdx.x;
    if (j >= KP) return;
    int c = *cnt2;
    float m = (j < c) ? 1.f : 0.f;
    int o = keep2[j];
    float4 d = dets[o];
    outD[j*4+0] = d.x*m; outD[j*4+1] = d.y*m; outD[j*4+2] = d.z*m; outD[j*4+3] = d.w*m;
    outS[j] = scores2[o]*m;
}

// ---------------- host ----------------
extern "C" void kernel_launch(void* const* d_in, const int* in_sizes, int n_in,
                              void* d_out, int out_size, void* d_ws, size_t ws_size,
                              hipStream_t stream) {
    const float* x     = (const float*)d_in[0];
    const float* bb_w  = (const float*)d_in[1];
    const float* bb_b  = (const float*)d_in[2];
    const float* rpn_w = (const float*)d_in[3];
    const float* rpn_b = (const float*)d_in[4];
    const float* rcw   = (const float*)d_in[5];
    const float* rcb   = (const float*)d_in[6];
    const float* rrw   = (const float*)d_in[7];
    const float* rrb   = (const float*)d_in[8];
    const float* fc1w  = (const float*)d_in[9];
    const float* fc1b  = (const float*)d_in[10];
    const float* fc2w  = (const float*)d_in[11];
    const float* fc2b  = (const float*)d_in[12];
    const float* clsw  = (const float*)d_in[13];
    const float* clsb  = (const float*)d_in[14];
    const float* regw  = (const float*)d_in[15];
    const float* regb  = (const float*)d_in[16];
    float* out = (float*)d_out;

    char* base = (char*)d_ws;
    size_t off = 0;
    auto carve = [&](size_t bytes) -> void* {
        void* r = base + off;
        off = (off + bytes + 255) & ~(size_t)255;
        return r;
    };
    // persistent
    double* featD   = (double*)carve((size_t)FHW*FHW*CCH*8);
    float*  featF   = (float*)carve((size_t)FHW*FHW*CCH*4);
    double* hD      = (double*)carve((size_t)FHW*FHW*CCH*8);
    double* wbTD    = (double*)carve((size_t)768*CCH*8);
    double* wTD     = (double*)carve((size_t)9*CCH*CCH*8);
    float*  propsF  = (float*)carve((size_t)KP*16);
    int*    cnt1    = (int*)carve(256);
    int*    cnt2    = (int*)carve(256);
    float*  scores2F= (float*)carve((size_t)KP*4);
    float*  dets2F  = (float*)carve((size_t)KP*16);
    int*    order2  = (int*)carve(KP*4);
    float4* sb2F    = (float4*)carve((size_t)KP*16);
    ull*    mask2   = (ull*)carve((size_t)KP*NW2*8);
    int*    keep2   = (int*)carve(KP*4);
    size_t mark = off;
    // phase A (RPN + NMS1)
    float*  boxesF  = (float*)carve((size_t)NAq*16);
    float*  scoresF = (float*)carve((size_t)NAq*4);
    int*    order1  = (int*)carve((size_t)NAq*4);
    float4* sb1F    = (float4*)carve((size_t)NAq*16);
    ull*    mask1   = (ull*)carve((size_t)NAq*NW1*8);
    int*    keep1   = (int*)carve(KP*4);
    // phase B overlaps phase A
    off = mark;
    float*  pooledF = (float*)carve((size_t)KP*KFC1*4);
    float*  h1F     = (float*)carve((size_t)KP*HID*4);
    float*  h2F     = (float*)carve((size_t)KP*HID*4);
    (void)ws_size; (void)in_sizes; (void)n_in; (void)out_size;

    // 1. anchors -> d_out (f32 reference ops)
    anchors_k<<<(NAq+255)/256, 256, 0, stream>>>(out + OFF_ANCH);
    // 2. weight transposes
    transb_k<<<(768*CCH+255)/256, 256, 0, stream>>>(bb_w, wbTD);
    transw_k<<<(9*CCH*CCH+255)/256, 256, 0, stream>>>(rpn_w, wTD);
    // 3. backbone (f64 + f32 copies)
    backbone_k<<<dim3(FHW, FHW), 128, 0, stream>>>(x, wbTD, bb_b, featD, featF);
    // 4. rpn conv (f64)
    rpnconv_k<<<dim3(FHW, FHW), 128, 0, stream>>>(featD, wTD, rpn_b, hD);
    // 5. rpn heads (f64 dot, f32 downstream)
    rpnhead_k<<<FHW*FHW, 64, 0, stream>>>(hD, rcw, rcb, rrw, rrb,
                                          out + OFF_LOGITS, out + OFF_DELTAS, boxesF, scoresF);
    // 6-9. NMS #1 (f32)
    rank_sortf<<<(NAq+255)/256, 256, 0, stream>>>(scoresF, order1, NAq);
    gather_sorted<<<(NAq+255)/256, 256, 0, stream>>>((const float4*)boxesF, order1, sb1F, NAq);
    nms_maskb<<<NAq, 64, 0, stream>>>(sb1F, mask1, NAq, NW1, 0.5f);
    nms_scan2<<<1, 64, 0, stream>>>(mask1, order1, keep1, cnt1, NAq, NW1, KP, 1);
    // 10. proposals
    props_k<<<(KP+255)/256, 256, 0, stream>>>((const float4*)boxesF, keep1,
                                              out + OFF_PROPS, (float4*)propsF);
    // 11. crop + pool (f32)
    croppool_k<<<KP, 128, 0, stream>>>(featF, propsF, pooledF);
    // 12-13. FCs (f64 accum, f32 io)
    gemm_nt_f<<<dim3(HID/64, (KP+63)/64), 256, 0, stream>>>(pooledF, fc1w, fc1b, h1F, KP, HID, KFC1);
    gemm_nt_f<<<dim3(HID/64, (KP+63)/64), 256, 0, stream>>>(h1F, fc2w, fc2b, h2F, KP, HID, HID);
    // 14. rcnn heads
    rcnnhead_k<<<KP, 64, 0, stream>>>(h2F, clsw, clsb, regw, regb, propsF,
                                      out + OFF_RLOG, out + OFF_RDEL, dets2F, scores2F);
    // 15-18. NMS #2 (f32)
    rank_sortf<<<(KP+255)/256, 256, 0, stream>>>(scores2F, order2, KP);
    gather_sorted<<<(KP+255)/256, 256, 0, stream>>>((const float4*)dets2F, order2, sb2F, KP);
    nms_maskb<<<KP, 64, 0, stream>>>(sb2F, mask2, KP, NW2, 0.3f);
    nms_scan2<<<1, 64, 0, stream>>>(mask2, order2, keep2, cnt2, KP, NW2, KP, 0);
    // 19. outputs
    finalize_k<<<(KP+255)/256, 256, 0, stream>>>((const float4*)dets2F, scores2F, keep2, cnt2,
                                                 out + OFF_DETS, out + OFF_SC);
}

// Round 10
// 3202.022 us; speedup vs baseline: 5.5998x; 1.2553x over previous
//
#include <hip/hip_runtime.h>
#include <cstdint>
#include <cstddef>

// ---------------- constants ----------------
#define FHW   32
#define CCH   128
#define NAq   9216
#define NW1   144
#define KP    2000
#define NW2   32
#define HID   1024
#define KFC1  6272

// output offsets (floats)
#define OFF_LOGITS 0
#define OFF_DELTAS 18432
#define OFF_PROPS  55296
#define OFF_ANCH   63296
#define OFF_RLOG   100160
#define OFF_RDEL   104160
#define OFF_DETS   112160
#define OFF_SC     120160

typedef unsigned long long ull;

// f32 anchor, replicating reference op order exactly
__device__ __forceinline__ void anchor_f32(int n, float* a4){
    int a = n % 9, j = (n/9) % FHW, i = n / (9*FHW);
    const float scales[3] = {32.f, 64.f, 128.f};
    const float ratios[3] = {0.5f, 1.f, 2.f};
    float s = scales[a/3], r = ratios[a%3];
    float sq = sqrtf(r);
    float ws = s / sq, hs = s * sq;
    float cx = ((float)j + 0.5f) * 16.f, cy = ((float)i + 0.5f) * 16.f;
    float W2 = ws * 0.5f, H2 = hs * 0.5f;
    a4[0] = cx - W2; a4[1] = cy - H2; a4[2] = cx + W2; a4[3] = cy + H2;
}

__global__ void anchors_k(float* __restrict__ outA){
    int n = blockIdx.x*blockDim.x + threadIdx.x;
    if (n >= NAq) return;
    float a4[4]; anchor_f32(n, a4);
    ((float4*)outA)[n] = make_float4(a4[0], a4[1], a4[2], a4[3]);
}

// ---------------- weight transposes (f32 -> f64) ----------------
__global__ void transb_k(const float* __restrict__ w, double* __restrict__ wT){
    int idx = blockIdx.x*blockDim.x + threadIdx.x;
    if (idx >= CCH*768) return;
    int oc = idx / 768, t = idx % 768;
    wT[t*CCH + oc] = (double)w[idx];
}
__global__ void transw_k(const float* __restrict__ w, double* __restrict__ wT){
    int idx = blockIdx.x*blockDim.x + threadIdx.x;
    if (idx >= CCH*CCH*9) return;
    int oc = idx / (CCH*9);
    int rem = idx % (CCH*9);
    int ic = rem / 9, p = rem % 9;
    wT[(p*CCH + ic)*CCH + oc] = (double)w[idx];
}

// ---------------- backbone conv (f64 accum), writes f64 + f32 copies ----------------
__global__ __launch_bounds__(128) void backbone_k(const float* __restrict__ x,
    const double* __restrict__ wT, const float* __restrict__ b,
    double* __restrict__ featD, float* __restrict__ featF){
    __shared__ double patch[768];
    int j = blockIdx.x, i = blockIdx.y, tid = threadIdx.x;
    for (int t = tid; t < 768; t += 128){
        int ch = t >> 8, rem = t & 255, r = rem >> 4, cl = rem & 15;
        patch[t] = (double)x[ch*512*512 + (i*16 + r)*512 + j*16 + cl];
    }
    __syncthreads();
    double acc = (double)b[tid];
    #pragma unroll 4
    for (int t = 0; t < 768; t++) acc += patch[t] * wT[t*CCH + tid];
    double v = fmax(acc, 0.0);
    featD[(i*FHW + j)*CCH + tid] = v;
    featF[(i*FHW + j)*CCH + tid] = (float)v;
}

// ---------------- rpn 3x3 conv (f64) ----------------
__global__ __launch_bounds__(128) void rpnconv_k(const double* __restrict__ feat,
    const double* __restrict__ wT, const float* __restrict__ b,
    double* __restrict__ h){
    __shared__ double patch[9*CCH];
    int j = blockIdx.x, i = blockIdx.y, tid = threadIdx.x;
    for (int t = tid; t < 9*CCH; t += 128){
        int p = t >> 7, ic = t & 127;
        int y = i + p/3 - 1, xx = j + p%3 - 1;
        patch[t] = (y >= 0 && y < FHW && xx >= 0 && xx < FHW) ? feat[(y*FHW + xx)*CCH + ic] : 0.0;
    }
    __syncthreads();
    double acc = (double)b[tid];
    #pragma unroll 4
    for (int t = 0; t < 9*CCH; t++) acc += patch[t] * wT[t*CCH + tid];
    h[(i*FHW + j)*CCH + tid] = fmax(acc, 0.0);
}

// ---------------- rpn heads: f64 dot, f32 softmax/decode/clip ----------------
__global__ __launch_bounds__(64) void rpnhead_k(const double* __restrict__ h,
    const float* __restrict__ wc, const float* __restrict__ bc,
    const float* __restrict__ wr, const float* __restrict__ br,
    float* __restrict__ outLog, float* __restrict__ outDel,
    float* __restrict__ boxes, float* __restrict__ scores){
    __shared__ double hv[CCH];
    __shared__ double ov[54];
    int pos = blockIdx.x, tid = threadIdx.x;
    hv[tid]      = h[pos*CCH + tid];
    hv[tid + 64] = h[pos*CCH + tid + 64];
    __syncthreads();
    if (tid < 54){
        const float* wrow; double bias;
        if (tid < 18){ wrow = wc + tid*CCH; bias = (double)bc[tid]; }
        else         { wrow = wr + (tid-18)*CCH; bias = (double)br[tid-18]; }
        double acc = bias;
        #pragma unroll 4
        for (int k = 0; k < CCH; k++) acc += hv[k] * (double)wrow[k];
        ov[tid] = acc;
    }
    __syncthreads();
    if (tid < 18) outLog[pos*18 + tid] = (float)ov[tid];
    if (tid < 36) outDel[pos*36 + tid] = (float)ov[18 + tid];
    if (tid < 9){
        int n = pos*9 + tid;
        float l0 = (float)ov[2*tid], l1 = (float)ov[2*tid+1];
        float m = fmaxf(l0, l1);
        float e0 = expf(l0 - m), e1 = expf(l1 - m);
        float s = e1 / (e0 + e1);
        float dx = (float)ov[18+4*tid+0], dy = (float)ov[18+4*tid+1];
        float dw = (float)ov[18+4*tid+2], dh = (float)ov[18+4*tid+3];
        float an[4]; anchor_f32(n, an);
        float aw = an[2] - an[0] + 1.f, ah = an[3] - an[1] + 1.f;
        float acx = an[0] + 0.5f*aw, acy = an[1] + 0.5f*ah;
        float pcx = dx*aw + acx, pcy = dy*ah + acy;
        float pw = expf(dw)*aw, ph = expf(dh)*ah;
        float x1 = pcx - 0.5f*pw, y1 = pcy - 0.5f*ph;
        float x2 = pcx + 0.5f*pw, y2 = pcy + 0.5f*ph;
        x1 = fminf(fmaxf(x1, 0.f), 511.f);  y1 = fminf(fmaxf(y1, 0.f), 511.f);
        x2 = fminf(fmaxf(x2, 0.f), 511.f);  y2 = fminf(fmaxf(y2, 0.f), 511.f);
        ((float4*)boxes)[n] = make_float4(x1, y1, x2, y2);
        scores[n] = s;
    }
}

// ---------------- stable rank sort (desc score, asc index), f32 ----------------
__global__ __launch_bounds__(256) void rank_sortf(const float* __restrict__ sc,
                                                  int* __restrict__ order, int N){
    __shared__ float ss[2048];
    int i = blockIdx.x*blockDim.x + threadIdx.x;
    float mys = (i < N) ? sc[i] : -1e30f;
    int r = 0;
    for (int base = 0; base < N; base += 2048){
        int cnt = min(2048, N - base);
        __syncthreads();
        for (int t = threadIdx.x; t < cnt; t += blockDim.x) ss[t] = sc[base + t];
        __syncthreads();
        for (int j = 0; j < cnt; j++){
            float s = ss[j];
            int jg = base + j;
            r += (s > mys) || (s == mys && jg < i);
        }
    }
    if (i < N) order[r] = i;
}

__global__ void gather_sorted(const float4* __restrict__ boxes, const int* __restrict__ order,
                              float4* __restrict__ sb, int N){
    int r = blockIdx.x*blockDim.x + threadIdx.x;
    if (r < N) sb[r] = boxes[order[r]];
}

// ---------------- IoU suppression bitmask via ballot: 1 wave per box i ----------------
__global__ __launch_bounds__(64) void nms_maskb(const float4* __restrict__ sb,
                          ull* __restrict__ mask, int N, int Nw, float thr){
    int i = blockIdx.x;
    int lane = threadIdx.x;
    float4 bi = sb[i];
    float areai = (bi.z - bi.x + 1.f) * (bi.w - bi.y + 1.f);
    int w0 = i >> 6;
    for (int w = w0; w < Nw; w++){
        int j = w*64 + lane;
        bool sup = false;
        if (j < N && j > i){
            float4 bj = sb[j];
            float xx1 = fmaxf(bi.x, bj.x), yy1 = fmaxf(bi.y, bj.y);
            float xx2 = fminf(bi.z, bj.z), yy2 = fminf(bi.w, bj.w);
            float iw = fmaxf(xx2 - xx1 + 1.f, 0.f), ih = fmaxf(yy2 - yy1 + 1.f, 0.f);
            float inter = iw * ih;
            float areaj = (bj.z - bj.x + 1.f) * (bj.w - bj.y + 1.f);
            float iou = inter / (areai + areaj - inter);
            sup = iou > thr;
        }
        ull bits = __ballot(sup);
        if (lane == 0) mask[(size_t)i*Nw + w] = bits;
    }
}

// ---------------- chunk-deferred greedy scan (1 wave), pipelined batch-OR ----------------
__global__ __launch_bounds__(64) void nms_scan2(const ull* __restrict__ mask,
                          const int* __restrict__ order,
                          int* __restrict__ keep, int* __restrict__ cntOut,
                          int N, int Nw, int K, int earlyStop){
    __shared__ ull removed[NW1];
    __shared__ ull diag[64];
    __shared__ int keptIdx[64];
    int tid = threadIdx.x;
    for (int t = tid; t < Nw; t += 64) removed[t] = 0ull;
    for (int t = tid; t < K;  t += 64) keep[t] = 0;
    __syncthreads();
    int cnt = 0;
    bool done = false;
    for (int iw = 0; iw < Nw && !done; ++iw){
        int i0 = iw << 6;
        int lim = N - i0; if (lim > 64) lim = 64;
        if (tid < lim) diag[tid] = mask[(size_t)(i0 + tid)*Nw + iw];
        __syncthreads();
        ull pending = ~removed[iw];
        if (lim < 64) pending &= (1ull << lim) - 1ull;
        int nk = 0;
        while (pending){
            int b = __builtin_ctzll(pending);
            if (tid == 0 && cnt < K) keep[cnt] = order[i0 + b];
            keptIdx[nk] = i0 + b;          // same value from every lane — benign
            nk++; cnt++;
            if (earlyStop && cnt >= K){ done = true; break; }
            pending &= ~(1ull << b);
            pending &= ~diag[b];           // LDS broadcast read
        }
        if (done) break;
        __syncthreads();
        // lanes own words w; loop r inside so the global loads pipeline
        for (int w = iw + 1 + tid; w < Nw; w += 64){
            ull accu = 0ull;
            int r = 0;
            for (; r + 4 <= nk; r += 4){
                ull m0 = mask[(size_t)keptIdx[r+0]*Nw + w];
                ull m1 = mask[(size_t)keptIdx[r+1]*Nw + w];
                ull m2 = mask[(size_t)keptIdx[r+2]*Nw + w];
                ull m3 = mask[(size_t)keptIdx[r+3]*Nw + w];
                accu |= (m0 | m1) | (m2 | m3);
            }
            for (; r < nk; r++) accu |= mask[(size_t)keptIdx[r]*Nw + w];
            removed[w] |= accu;
        }
        __syncthreads();
    }
    if (tid == 0) *cntOut = cnt;
}

// ---------------- gather proposals ----------------
__global__ void props_k(const float4* __restrict__ boxes, const int* __restrict__ keep1,
                        float* __restrict__ outP, float4* __restrict__ propsWs){
    int j = blockIdx.x*blockDim.x + threadIdx.x;
    if (j >= KP) return;
    float4 b = boxes[keep1[j]];
    ((float4*)outP)[j] = b;
    propsWs[j] = b;
}

// ---------------- crop_resize(14) + 2x2 maxpool, f32 ----------------
__global__ __launch_bounds__(128) void croppool_k(const float* __restrict__ feat,
    const float* __restrict__ props, float* __restrict__ pooled){
    __shared__ int   sy0[14], sy1[14], sx0[14], sx1[14];
    __shared__ float swy[14], swx[14];
    int n = blockIdx.x, tid = threadIdx.x;
    const float* p = props + n*4;
    if (tid < 28){
        int s = tid % 14;
        bool isx = tid >= 14;
        float c1 = (isx ? p[0] : p[1]) / 511.f;   // nb reorder [1,0,3,2]
        float c2 = (isx ? p[2] : p[3]) / 511.f;
        float t = (float)s / 13.f;
        float v = (c1 + t * (c2 - c1)) * 31.f;
        int v0 = (int)floorf(v);
        v0 = v0 < 0 ? 0 : (v0 > 31 ? 31 : v0);
        int v1i = v0 + 1; if (v1i > 31) v1i = 31;
        float wv = v - (float)v0;
        if (isx){ sx0[s]=v0; sx1[s]=v1i; swx[s]=wv; }
        else    { sy0[s]=v0; sy1[s]=v1i; swy[s]=wv; }
    }
    __syncthreads();
    int c = tid;
    float* outr = pooled + (size_t)n*KFC1 + c*49;
    for (int py = 0; py < 7; py++){
        for (int px = 0; px < 7; px++){
            float mx = -3.402823466e38f;
            #pragma unroll
            for (int dy = 0; dy < 2; dy++){
                #pragma unroll
                for (int dx = 0; dx < 2; dx++){
                    int sy = 2*py + dy, sx = 2*px + dx;
                    int y0 = sy0[sy], y1 = sy1[sy], x0 = sx0[sx], x1 = sx1[sx];
                    float wy = swy[sy], wx = swx[sx];
                    float f00 = feat[(y0*FHW + x0)*CCH + c];
                    float f01 = feat[(y0*FHW + x1)*CCH + c];
                    float f10 = feat[(y1*FHW + x0)*CCH + c];
                    float f11 = feat[(y1*FHW + x1)*CCH + c];
                    float top = f00*(1.f - wx) + f01*wx;
                    float bot = f10*(1.f - wx) + f11*wx;
                    float val = top*(1.f - wy) + bot*wy;
                    mx = fmaxf(mx, val);
                }
            }
            outr[py*7 + px] = mx;
        }
    }
}

// ---------------- tiled GEMM: C = A(MxK) * B(NxK)^T + bias, f64 accum, relu ----------------
// Double-buffered LDS + register prefetch (float4). Same summation order as before
// (k ascending) -> bit-identical output.
__global__ __launch_bounds__(256) void gemm_nt_f(const float* __restrict__ A,
    const float* __restrict__ B, const float* __restrict__ bias,
    float* __restrict__ C, int M, int N, int K){
    __shared__ float As[2][64][33];
    __shared__ float Bs[2][64][33];
    int tid = threadIdx.x;
    int tx = tid & 15, ty = tid >> 4;
    int m0 = blockIdx.y*64, n0 = blockIdx.x*64;
    int ra = tid >> 3;              // rows 0..31
    int ca = (tid & 7) << 2;        // cols 0,4,...,28
    int rb = ra + 32;               // rows 32..63
    double acc[4][4];
    #pragma unroll
    for (int r = 0; r < 4; r++)
        #pragma unroll
        for (int c = 0; c < 4; c++) acc[r][c] = 0.0;

    const float4 z4 = make_float4(0.f, 0.f, 0.f, 0.f);
    float4 av0, av1, bv0, bv1;
    int gm0 = m0 + ra, gm1 = m0 + rb;
    int gn0 = n0 + ra, gn1 = n0 + rb;

    // fetch tile at k0 into registers
    auto fetch = [&](int k0){
        av0 = (gm0 < M) ? *(const float4*)(A + (size_t)gm0*K + k0 + ca) : z4;
        av1 = (gm1 < M) ? *(const float4*)(A + (size_t)gm1*K + k0 + ca) : z4;
        bv0 = (gn0 < N) ? *(const float4*)(B + (size_t)gn0*K + k0 + ca) : z4;
        bv1 = (gn1 < N) ? *(const float4*)(B + (size_t)gn1*K + k0 + ca) : z4;
    };
    auto stash = [&](int buf){
        As[buf][ra][ca+0]=av0.x; As[buf][ra][ca+1]=av0.y; As[buf][ra][ca+2]=av0.z; As[buf][ra][ca+3]=av0.w;
        As[buf][rb][ca+0]=av1.x; As[buf][rb][ca+1]=av1.y; As[buf][rb][ca+2]=av1.z; As[buf][rb][ca+3]=av1.w;
        Bs[buf][ra][ca+0]=bv0.x; Bs[buf][ra][ca+1]=bv0.y; Bs[buf][ra][ca+2]=bv0.z; Bs[buf][ra][ca+3]=bv0.w;
        Bs[buf][rb][ca+0]=bv1.x; Bs[buf][rb][ca+1]=bv1.y; Bs[buf][rb][ca+2]=bv1.z; Bs[buf][rb][ca+3]=bv1.w;
    };

    fetch(0);
    stash(0);
    __syncthreads();
    int nt = K >> 5;
    int cur = 0;
    for (int t = 0; t < nt; t++){
        bool more = (t + 1 < nt);
        if (more) fetch((t + 1) << 5);     // issue loads; latency hides under compute
        #pragma unroll
        for (int k = 0; k < 32; k++){
            float avr[4], bvr[4];
            #pragma unroll
            for (int r = 0; r < 4; r++) avr[r] = As[cur][ty*4 + r][k];
            #pragma unroll
            for (int c = 0; c < 4; c++) bvr[c] = Bs[cur][tx*4 + c][k];
            #pragma unroll
            for (int r = 0; r < 4; r++)
                #pragma unroll
                for (int c = 0; c < 4; c++) acc[r][c] += (double)avr[r]*(double)bvr[c];
        }
        if (more) stash(cur ^ 1);          // other buffer: safe to write while peers compute
        __syncthreads();
        cur ^= 1;
    }
    #pragma unroll
    for (int r = 0; r < 4; r++){
        int gm = m0 + ty*4 + r;
        if (gm >= M) continue;
        #pragma unroll
        for (int c = 0; c < 4; c++){
            int gn = n0 + tx*4 + c;
            double v = acc[r][c] + (double)bias[gn];
            C[(size_t)gm*N + gn] = (float)fmax(v, 0.0);
        }
    }
}

// ---------------- rcnn heads: f64 dot, f32 softmax/decode/clip ----------------
__global__ __launch_bounds__(64) void rcnnhead_k(const float* __restrict__ h2,
    const float* __restrict__ wcls, const float* __restrict__ bcls,
    const float* __restrict__ wreg, const float* __restrict__ breg,
    const float* __restrict__ props,
    float* __restrict__ outLog, float* __restrict__ outDel,
    float* __restrict__ dets, float* __restrict__ scores2){
    int n = blockIdx.x, tid = threadIdx.x;
    const float* hr = h2 + (size_t)n*HID;
    double s[6];
    #pragma unroll
    for (int o = 0; o < 6; o++){
        const float* wrow = (o < 2) ? (wcls + o*HID) : (wreg + (o-2)*HID);
        double a = 0.0;
        for (int k = tid; k < HID; k += 64) a += (double)hr[k] * (double)wrow[k];
        #pragma unroll
        for (int off = 32; off > 0; off >>= 1) a += __shfl_down(a, off, 64);
        s[o] = a;
    }
    if (tid == 0){
        float l0 = (float)(s[0] + (double)bcls[0]), l1 = (float)(s[1] + (double)bcls[1]);
        outLog[n*2 + 0] = l0; outLog[n*2 + 1] = l1;
        float dx = (float)(s[2] + (double)breg[0]), dy = (float)(s[3] + (double)breg[1]);
        float dw = (float)(s[4] + (double)breg[2]), dh = (float)(s[5] + (double)breg[3]);
        outDel[n*4+0] = dx; outDel[n*4+1] = dy; outDel[n*4+2] = dw; outDel[n*4+3] = dh;
        float mm = fmaxf(l0, l1);
        float e0 = expf(l0 - mm), e1 = expf(l1 - mm);
        float sc = e1 / (e0 + e1);
        scores2[n] = sc;
        const float* an = props + n*4;
        float aw = an[2]-an[0]+1.f, ah = an[3]-an[1]+1.f;
        float acx = an[0] + 0.5f*aw, acy = an[1] + 0.5f*ah;
        float pcx = dx*aw + acx, pcy = dy*ah + acy;
        float pw = expf(dw)*aw, ph = expf(dh)*ah;
        float x1 = pcx - 0.5f*pw, y1 = pcy - 0.5f*ph;
        float x2 = pcx + 0.5f*pw, y2 = pcy + 0.5f*ph;
        x1 = fminf(fmaxf(x1, 0.f), 511.f);  y1 = fminf(fmaxf(y1, 0.f), 511.f);
        x2 = fminf(fmaxf(x2, 0.f), 511.f);  y2 = fminf(fmaxf(y2, 0.f), 511.f);
        dets[n*4+0] = x1; dets[n*4+1] = y1; dets[n*4+2] = x2; dets[n*4+3] = y2;
    }
}

// ---------------- final masked gather ----------------
__global__ void finalize_k(const float4* __restrict__ dets, const float* __restrict__ scores2,
                           const int* __restrict__ keep2, const int* __restrict__ cnt2,
                           float* __restrict__ outD, float* __restrict__ outS){
    int j = blockIdx.x*blockDim.x + threadIdx.x;
    if (j >= KP) return;
    int c = *cnt2;
    float m = (j < c) ? 1.f : 0.f;
    int o = keep2[j];
    float4 d = dets[o];
    outD[j*4+0] = d.x*m; outD[j*4+1] = d.y*m; outD[j*4+2] = d.z*m; outD[j*4+3] = d.w*m;
    outS[j] = scores2[o]*m;
}

// ---------------- host ----------------
extern "C" void kernel_launch(void* const* d_in, const int* in_sizes, int n_in,
                              void* d_out, int out_size, void* d_ws, size_t ws_size,
                              hipStream_t stream) {
    const float* x     = (const float*)d_in[0];
    const float* bb_w  = (const float*)d_in[1];
    const float* bb_b  = (const float*)d_in[2];
    const float* rpn_w = (const float*)d_in[3];
    const float* rpn_b = (const float*)d_in[4];
    const float* rcw   = (const float*)d_in[5];
    const float* rcb   = (const float*)d_in[6];
    const float* rrw   = (const float*)d_in[7];
    const float* rrb   = (const float*)d_in[8];
    const float* fc1w  = (const float*)d_in[9];
    const float* fc1b  = (const float*)d_in[10];
    const float* fc2w  = (const float*)d_in[11];
    const float* fc2b  = (const float*)d_in[12];
    const float* clsw  = (const float*)d_in[13];
    const float* clsb  = (const float*)d_in[14];
    const float* regw  = (const float*)d_in[15];
    const float* regb  = (const float*)d_in[16];
    float* out = (float*)d_out;

    char* base = (char*)d_ws;
    size_t off = 0;
    auto carve = [&](size_t bytes) -> void* {
        void* r = base + off;
        off = (off + bytes + 255) & ~(size_t)255;
        return r;
    };
    // persistent
    double* featD   = (double*)carve((size_t)FHW*FHW*CCH*8);
    float*  featF   = (float*)carve((size_t)FHW*FHW*CCH*4);
    double* hD      = (double*)carve((size_t)FHW*FHW*CCH*8);
    double* wbTD    = (double*)carve((size_t)768*CCH*8);
    double* wTD     = (double*)carve((size_t)9*CCH*CCH*8);
    float*  propsF  = (float*)carve((size_t)KP*16);
    int*    cnt1    = (int*)carve(256);
    int*    cnt2    = (int*)carve(256);
    float*  scores2F= (float*)carve((size_t)KP*4);
    float*  dets2F  = (float*)carve((size_t)KP*16);
    int*    order2  = (int*)carve(KP*4);
    float4* sb2F    = (float4*)carve((size_t)KP*16);
    ull*    mask2   = (ull*)carve((size_t)KP*NW2*8);
    int*    keep2   = (int*)carve(KP*4);
    size_t mark = off;
    // phase A (RPN + NMS1)
    float*  boxesF  = (float*)carve((size_t)NAq*16);
    float*  scoresF = (float*)carve((size_t)NAq*4);
    int*    order1  = (int*)carve((size_t)NAq*4);
    float4* sb1F    = (float4*)carve((size_t)NAq*16);
    ull*    mask1   = (ull*)carve((size_t)NAq*NW1*8);
    int*    keep1   = (int*)carve(KP*4);
    // phase B overlaps phase A
    off = mark;
    float*  pooledF = (float*)carve((size_t)KP*KFC1*4);
    float*  h1F     = (float*)carve((size_t)KP*HID*4);
    float*  h2F     = (float*)carve((size_t)KP*HID*4);
    (void)ws_size; (void)in_sizes; (void)n_in; (void)out_size;

    // 1. anchors -> d_out (f32 reference ops)
    anchors_k<<<(NAq+255)/256, 256, 0, stream>>>(out + OFF_ANCH);
    // 2. weight transposes
    transb_k<<<(768*CCH+255)/256, 256, 0, stream>>>(bb_w, wbTD);
    transw_k<<<(9*CCH*CCH+255)/256, 256, 0, stream>>>(rpn_w, wTD);
    // 3. backbone (f64 + f32 copies)
    backbone_k<<<dim3(FHW, FHW), 128, 0, stream>>>(x, wbTD, bb_b, featD, featF);
    // 4. rpn conv (f64)
    rpnconv_k<<<dim3(FHW, FHW), 128, 0, stream>>>(featD, wTD, rpn_b, hD);
    // 5. rpn heads (f64 dot, f32 downstream)
    rpnhead_k<<<FHW*FHW, 64, 0, stream>>>(hD, rcw, rcb, rrw, rrb,
                                          out + OFF_LOGITS, out + OFF_DELTAS, boxesF, scoresF);
    // 6-9. NMS #1 (f32)
    rank_sortf<<<(NAq+255)/256, 256, 0, stream>>>(scoresF, order1, NAq);
    gather_sorted<<<(NAq+255)/256, 256, 0, stream>>>((const float4*)boxesF, order1, sb1F, NAq);
    nms_maskb<<<NAq, 64, 0, stream>>>(sb1F, mask1, NAq, NW1, 0.5f);
    nms_scan2<<<1, 64, 0, stream>>>(mask1, order1, keep1, cnt1, NAq, NW1, KP, 1);
    // 10. proposals
    props_k<<<(KP+255)/256, 256, 0, stream>>>((const float4*)boxesF, keep1,
                                              out + OFF_PROPS, (float4*)propsF);
    // 11. crop + pool (f32)
    croppool_k<<<KP, 128, 0, stream>>>(featF, propsF, pooledF);
    // 12-13. FCs (f64 accum, f32 io)
    gemm_nt_f<<<dim3(HID/64, (KP+63)/64), 256, 0, stream>>>(pooledF, fc1w, fc1b, h1F, KP, HID, KFC1);
    gemm_nt_f<<<dim3(HID/64, (KP+63)/64), 256, 0, stream>>>(h1F, fc2w, fc2b, h2F, KP, HID, HID);
    // 14. rcnn heads
    rcnnhead_k<<<KP, 64, 0, stream>>>(h2F, clsw, clsb, regw, regb, propsF,
                                      out + OFF_RLOG, out + OFF_RDEL, dets2F, scores2F);
    // 15-18. NMS #2 (f32)
    rank_sortf<<<(KP+255)/256, 256, 0, stream>>>(scores2F, order2, KP);
    gather_sorted<<<(KP+255)/256, 256, 0, stream>>>((const float4*)dets2F, order2, sb2F, KP);
    nms_maskb<<<KP, 64, 0, stream>>>(sb2F, mask2, KP, NW2, 0.3f);
    nms_scan2<<<1, 64, 0, stream>>>(mask2, order2, keep2, cnt2, KP, NW2, KP, 0);
    // 19. outputs
    finalize_k<<<(KP+255)/256, 256, 0, stream>>>((const float4*)dets2F, scores2F, keep2, cnt2,
                                                 out + OFF_DETS, out + OFF_SC);
}